// Round 13
// baseline (438.033 us; speedup 1.0000x reference)
//
#include <hip/hip_runtime.h>

typedef unsigned short u16;
typedef _Float16 f16x8 __attribute__((ext_vector_type(8)));
typedef float f32x4 __attribute__((ext_vector_type(4)));
typedef u16 u16x4 __attribute__((ext_vector_type(4)));
typedef u16 u16x8v __attribute__((ext_vector_type(8)));

__device__ __forceinline__ u16 f2h(float f) {
    _Float16 h = (_Float16)f;
    return __builtin_bit_cast(u16, h);
}
__device__ __forceinline__ float h2f(u16 u) {
    return (float)__builtin_bit_cast(_Float16, u);
}

// ---------------------------------------------------------------- stats ----
__global__ void __launch_bounds__(256) stats_kernel(
    const float* __restrict__ c, const float* __restrict__ s,
    float* __restrict__ mC, float* __restrict__ rC,
    float* __restrict__ mS, float* __restrict__ rS)
{
    const float* src = (blockIdx.y ? s : c) + (size_t)blockIdx.x * 4096;
    int t = threadIdx.x, lane = t & 63, wv = t >> 6;
    const float4* p = (const float4*)src;
    float sum = 0.f, sq = 0.f;
#pragma unroll
    for (int i = 0; i < 4; ++i) {
        float4 v = p[t + 256 * i];
        sum += v.x + v.y + v.z + v.w;
        sq  += v.x * v.x + v.y * v.y + v.z * v.z + v.w * v.w;
    }
#pragma unroll
    for (int m = 1; m < 64; m <<= 1) {
        sum += __shfl_xor(sum, m);
        sq  += __shfl_xor(sq, m);
    }
    __shared__ float sa[4], sb[4];
    if (!lane) { sa[wv] = sum; sb[wv] = sq; }
    __syncthreads();
    if (t == 0) {
        float S = sa[0] + sa[1] + sa[2] + sa[3];
        float Q = sb[0] + sb[1] + sb[2] + sb[3];
        float mean = S * (1.0f / 4096.0f);
        float var = (Q - 4096.0f * mean * mean) * (1.0f / 4095.0f);
        float rstd = rsqrtf(var + 1e-5f);
        if (blockIdx.y) { mS[blockIdx.x] = mean; rS[blockIdx.x] = rstd; }
        else            { mC[blockIdx.x] = mean; rC[blockIdx.x] = rstd; }
    }
}

// ------------------------------------------------- fused transpose pack ----
__global__ void __launch_bounds__(256) packall(
    const float* __restrict__ c, const float* __restrict__ s,
    const float* __restrict__ mC, const float* __restrict__ rC,
    const float* __restrict__ mS, const float* __restrict__ rS,
    u16* __restrict__ cnT, u16* __restrict__ snT, u16* __restrict__ sRT)
{
    __shared__ float tile[32][33];
    int z = blockIdx.z;
    bool isS = z >= 4;
    int b = isS ? z - 4 : z;
    const float* src  = isS ? s : c;
    const float* mean = isS ? mS : mC;
    const float* rstd = isS ? rS : rC;
    u16* dh = isS ? snT : cnT;
    int n0 = blockIdx.x * 32, c0 = blockIdx.y * 32;
    int tx = threadIdx.x, ty = threadIdx.y;
    const float* sbp = src + ((size_t)b * 512 + c0) * 4096 + n0;
#pragma unroll
    for (int it = 0; it < 4; ++it) {
        int cc = ty + it * 8;
        tile[cc][tx] = sbp[(size_t)cc * 4096 + tx];
    }
    __syncthreads();
    int ch = c0 + tx;
    float mn = mean[b * 512 + ch];
    float rs = rstd[b * 512 + ch];
    size_t obase = ((size_t)b * 4096 + n0) * 512 + c0;
#pragma unroll
    for (int it = 0; it < 4; ++it) {
        int r = ty + it * 8;
        float v = tile[tx][r];
        size_t o = obase + (size_t)r * 512 + tx;
        dh[o] = f2h((v - mn) * rs);
        if (isS) sRT[o] = f2h(v);
    }
}

// ------------------------------------------------- fused weight prep ------
__global__ void __launch_bounds__(256) prep_kernel(
    const float* __restrict__ c_w, const float* __restrict__ s_w,
    const float* __restrict__ i_w, const float* __restrict__ o_w,
    u16* __restrict__ cwT, u16* __restrict__ swT,
    u16* __restrict__ iwT, u16* __restrict__ ow)
{
    int z = blockIdx.z;
    int tx = threadIdx.x, ty = threadIdx.y;
    if (z == 3) {
        size_t base = ((size_t)(blockIdx.y * 16 + blockIdx.x) * 256 +
                       (ty * 32 + tx)) * 4;
        float4 v = *(const float4*)(o_w + base);
        u16x4 o;
        o[0] = f2h(v.x); o[1] = f2h(v.y); o[2] = f2h(v.z); o[3] = f2h(v.w);
        *(u16x4*)(ow + base) = o;
        return;
    }
    const float* w = (z == 0) ? c_w : (z == 1) ? s_w : i_w;
    u16* wT = (z == 0) ? cwT : (z == 1) ? swT : iwT;
    __shared__ float tile[32][33];
    int c0 = blockIdx.x * 32, k0 = blockIdx.y * 32;
#pragma unroll
    for (int it = 0; it < 4; ++it) {
        int kk = ty + it * 8;
        tile[kk][tx] = w[(size_t)(k0 + kk) * 512 + c0 + tx];
    }
    __syncthreads();
#pragma unroll
    for (int it = 0; it < 4; ++it) {
        int r = ty + it * 8;
        wT[(size_t)(c0 + r) * 512 + k0 + tx] = f2h(tile[tx][r]);
    }
}

// ------------------------------------------------- fused bias prep --------
__global__ void __launch_bounds__(256) bias_prep(
    const float* __restrict__ o_w, const float* __restrict__ i_b,
    const float* __restrict__ o_b, const float* __restrict__ s_w,
    const float* __restrict__ c_b, float* __restrict__ v,
    float* __restrict__ wu)
{
    __shared__ float buf[512];
    int t = threadIdx.x;
    bool isWu = blockIdx.x >= 2;
    const float* vec = isWu ? c_b : i_b;
    buf[t] = vec[t]; buf[t + 256] = vec[t + 256];
    __syncthreads();
    int o = (blockIdx.x & 1) * 256 + t;
    if (!isWu) {
        float acc = o_b[o];
        const float* row = o_w + (size_t)o * 512;
        for (int k = 0; k < 512; ++k) acc += row[k] * buf[k];
        v[o] = acc;
    } else {
        float acc = 0.f;
        for (int k = 0; k < 512; ++k) acc += buf[k] * s_w[(size_t)k * 512 + o];
        wu[o] = acc;
    }
}

// u[r] = sum_l snT[r,l] * wu[l]
__global__ void __launch_bounds__(256) rowdot_kernel(
    const u16* __restrict__ snT, const float* __restrict__ wu,
    float* __restrict__ u)
{
    __shared__ float swu[512];
    int t = threadIdx.x;
    swu[t] = wu[t]; swu[t + 256] = wu[t + 256];
    __syncthreads();
    int lane = t & 63, wv = t >> 6;
    int row = blockIdx.x * 4 + wv;
    u16x8v h = *(const u16x8v*)(snT + (size_t)row * 512 + lane * 8);
    float acc = 0.f;
#pragma unroll
    for (int i = 0; i < 8; ++i) acc += h2f(h[i]) * swu[lane * 8 + i];
#pragma unroll
    for (int m = 1; m < 64; m <<= 1) acc += __shfl_xor(acc, m);
    if (!lane) u[row] = acc;
}

// ---------------------------------------------------------------- GEMM ----
// 256x128 tile, 512 threads (8 waves as 4M x 2N), BK=64.
// Depth-2 software pipeline: 3 LDS slots (48KB each, 147KB dynamic), tile
// t+2 staged while computing tile t; counted vmcnt(12)/(6)/(0) keeps 12
// loads in flight across barriers (T3/T4: never drain to 0 in steady state).
#define EPI_F32       0
#define EPI_PLAIN_F16 2
#define SLOT 49152

__device__ __forceinline__ void stageA(
    const u16* __restrict__ g, int ldk, int i0, int k0, char* tile, int wv, int lane)
{
#pragma unroll
    for (int cc = 0; cc < 4; ++cc) {
        int chunk = (wv * 4 + cc) * 64 + lane;   // 2048 chunks = 256 rows
        int row  = chunk >> 3;
        int slot = chunk & 7;
        int gc   = slot ^ (row & 7);
        const u16* gp = g + (size_t)(i0 + row) * ldk + (k0 + gc * 8);
        char* lp = tile + (size_t)(wv * 4 + cc) * 1024;
        __builtin_amdgcn_global_load_lds(
            (const __attribute__((address_space(1))) unsigned int*)gp,
            (__attribute__((address_space(3))) unsigned int*)lp, 16, 0, 0);
    }
}
__device__ __forceinline__ void stageB(
    const u16* __restrict__ g, int ldk, int j0, int k0, char* tile, int wv, int lane)
{
#pragma unroll
    for (int cc = 0; cc < 2; ++cc) {
        int chunk = (wv * 2 + cc) * 64 + lane;   // 1024 chunks = 128 rows
        int row  = chunk >> 3;
        int slot = chunk & 7;
        int gc   = slot ^ (row & 7);
        const u16* gp = g + (size_t)(j0 + row) * ldk + (k0 + gc * 8);
        char* lp = tile + (size_t)(wv * 2 + cc) * 1024;
        __builtin_amdgcn_global_load_lds(
            (const __attribute__((address_space(1))) unsigned int*)gp,
            (__attribute__((address_space(3))) unsigned int*)lp, 16, 0, 0);
    }
}

template<int EPI>
__global__ void __launch_bounds__(512) gemm_bt(
    const u16* __restrict__ A_, const u16* __restrict__ B_,
    int K, int ldk, const float* __restrict__ bias,
    const float* __restrict__ jb, long jbZ,
    float* __restrict__ outF_, u16* __restrict__ outH_,
    int ldo, int zdiv,
    long aBatch, long aChunk, long bBatch, long bChunk, long oZ)
{
    extern __shared__ char smem[];               // 3 slots x (A 32KB | B 16KB)

    int bz = blockIdx.z;
    int batch = bz / zdiv, chunk = bz % zdiv;
    const u16* A  = A_ + (size_t)batch * aBatch + (size_t)chunk * aChunk;
    const u16* Bm = B_ + (size_t)batch * bBatch + (size_t)chunk * bChunk;

    int i0 = blockIdx.y * 256, j0 = blockIdx.x * 128;
    int tid = threadIdx.x, lane = tid & 63, wv = tid >> 6;
    int wr = wv >> 1, wc = wv & 1;               // 4M x 2N waves, 64x64 each
    int r15 = lane & 15, h4 = lane >> 4;

    f32x4 zero = {0.f, 0.f, 0.f, 0.f};
    f32x4 acc[4][4];
#pragma unroll
    for (int m = 0; m < 4; ++m)
#pragma unroll
        for (int n = 0; n < 4; ++n) acc[m][n] = zero;

    int nk = K >> 6;
    // prologue: stage tiles 0 and 1 into slots 0 and 1
    stageA(A, ldk, i0, 0, smem, wv, lane);
    stageB(Bm, ldk, j0, 0, smem + 32768, wv, lane);
    if (nk > 1) {
        stageA(A, ldk, i0, 64, smem + SLOT, wv, lane);
        stageB(Bm, ldk, j0, 64, smem + SLOT + 32768, wv, lane);
    }

    int cs = 0, ns = 2;
    for (int t = 0; t < nk; ++t) {
        char* sAc = smem + cs * SLOT;
        char* sBc = sAc + 32768;
        if (t + 2 < nk) {
            char* sS = smem + ns * SLOT;
            stageA(A, ldk, i0, (t + 2) * 64, sS, wv, lane);
            stageB(Bm, ldk, j0, (t + 2) * 64, sS + 32768, wv, lane);
            // 18 outstanding -> 12: tile t's 6 retired; t+1/t+2 in flight
            asm volatile("s_waitcnt vmcnt(12)" ::: "memory");
            ns = (ns == 2) ? 0 : ns + 1;
        } else if (t + 1 < nk) {
            asm volatile("s_waitcnt vmcnt(6)" ::: "memory");
        } else {
            asm volatile("s_waitcnt vmcnt(0)" ::: "memory");
        }
        __syncthreads();
#pragma unroll
        for (int ks = 0; ks < 2; ++ks) {
            f16x8 a[4], b[4];
#pragma unroll
            for (int m = 0; m < 4; ++m) {
                int row = wr * 64 + m * 16 + r15;
                int off = row * 128 + (((ks * 4 + h4) ^ (row & 7)) << 4);
                a[m] = *(const f16x8*)(sAc + off);
            }
#pragma unroll
            for (int n = 0; n < 4; ++n) {
                int col = wc * 64 + n * 16 + r15;
                int off = col * 128 + (((ks * 4 + h4) ^ (col & 7)) << 4);
                b[n] = *(const f16x8*)(sBc + off);
            }
#pragma unroll
            for (int m = 0; m < 4; ++m)
#pragma unroll
                for (int n = 0; n < 4; ++n)
                    acc[m][n] = __builtin_amdgcn_mfma_f32_16x16x32_f16(a[m], b[n], acc[m][n], 0, 0, 0);
        }
        __syncthreads();   // all waves done with slot cs before it is restaged
        cs = (cs == 2) ? 0 : cs + 1;
    }

    float* outF = outF_ ? outF_ + (size_t)bz * oZ : nullptr;
    u16* outH = outH_ ? outH_ + (size_t)bz * oZ : nullptr;
    const float* jbp = jb ? jb + (size_t)bz * jbZ : nullptr;

#pragma unroll
    for (int m = 0; m < 4; ++m)
#pragma unroll
        for (int n = 0; n < 4; ++n) {
            int ibase = i0 + wr * 64 + m * 16 + h4 * 4;
            int j = j0 + wc * 64 + n * 16 + r15;
#pragma unroll
            for (int r = 0; r < 4; ++r) {
                int i = ibase + r;
                float v = acc[m][n][r];
                if constexpr (EPI == EPI_PLAIN_F16) {
                    if (bias) v += bias[i];
                    if (jbp) v += jbp[j];
                    outH[(size_t)i * ldo + j] = f2h(v);
                } else { // EPI_F32
                    outF[(size_t)i * ldo + j] = v;
                }
            }
        }
}

// ------------------------------------------------------ softmax (f16) ----
__global__ void __launch_bounds__(256) softmax16(u16* __restrict__ LP)
{
    u16x8v* row = (u16x8v*)(LP + (size_t)blockIdx.x * 4096);
    int t = threadIdx.x, lane = t & 63, wv = t >> 6;
    u16x8v ca = row[t], cb = row[t + 256];
    float va[8], vb[8];
    float mx = -3.4e38f;
#pragma unroll
    for (int i = 0; i < 8; ++i) {
        va[i] = h2f(ca[i]); vb[i] = h2f(cb[i]);
        mx = fmaxf(mx, fmaxf(va[i], vb[i]));
    }
#pragma unroll
    for (int m = 1; m < 64; m <<= 1) mx = fmaxf(mx, __shfl_xor(mx, m));
    __shared__ float sM[4], sS[4];
    if (!lane) sM[wv] = mx;
    __syncthreads();
    mx = fmaxf(fmaxf(sM[0], sM[1]), fmaxf(sM[2], sM[3]));
    float sum = 0.f;
#pragma unroll
    for (int i = 0; i < 8; ++i) {
        va[i] = __expf(va[i] - mx);
        vb[i] = __expf(vb[i] - mx);
        sum += va[i] + vb[i];
    }
#pragma unroll
    for (int m = 1; m < 64; m <<= 1) sum += __shfl_xor(sum, m);
    if (!lane) sS[wv] = sum;
    __syncthreads();
    sum = sS[0] + sS[1] + sS[2] + sS[3];
    float inv = 1.0f / sum;
    u16x8v oa, ob;
#pragma unroll
    for (int i = 0; i < 8; ++i) {
        oa[i] = f2h(va[i] * inv);
        ob[i] = f2h(vb[i] * inv);
    }
    row[t] = oa; row[t + 256] = ob;
}

// -------------------------------------- split-K reduce + residual + v -----
__global__ void __launch_bounds__(256) reduce4resid(
    const u16* __restrict__ part, const float* __restrict__ xr,
    const float* __restrict__ v, float* __restrict__ out)
{
    const size_t PLANE = 2097152;
    int b = blockIdx.y;
    size_t g8 = ((size_t)blockIdx.x * 256 + threadIdx.x) * 8;
    const u16* p0 = part + (size_t)b * 4 * PLANE + g8;
    float acc[8] = {0.f, 0.f, 0.f, 0.f, 0.f, 0.f, 0.f, 0.f};
#pragma unroll
    for (int k = 0; k < 4; ++k) {
        u16x8v h = *(const u16x8v*)(p0 + (size_t)k * PLANE);
#pragma unroll
        for (int i = 0; i < 8; ++i) acc[i] += h2f(h[i]);
    }
    const float4* xv = (const float4*)(xr + (size_t)b * PLANE + g8);
    float4 x0 = xv[0], x1 = xv[1];
    float vc = v[g8 >> 12];
    float4 o0, o1;
    o0.x = acc[0] + x0.x + vc; o0.y = acc[1] + x0.y + vc;
    o0.z = acc[2] + x0.z + vc; o0.w = acc[3] + x0.w + vc;
    o1.x = acc[4] + x1.x + vc; o1.y = acc[5] + x1.y + vc;
    o1.z = acc[6] + x1.z + vc; o1.w = acc[7] + x1.w + vc;
    float4* op = (float4*)(out + (size_t)b * PLANE + g8);
    op[0] = o0; op[1] = o1;
}

// -------------------------------------------------------------- launch ----
extern "C" void kernel_launch(void* const* d_in, const int* in_sizes, int n_in,
                              void* d_out, int out_size, void* d_ws, size_t ws_size,
                              hipStream_t stream)
{
    const float* c   = (const float*)d_in[0];
    const float* s   = (const float*)d_in[1];
    const float* x   = (const float*)d_in[2];
    const float* c_w = (const float*)d_in[3];
    const float* c_b = (const float*)d_in[4];
    const float* s_w = (const float*)d_in[5];
    const float* s_b = (const float*)d_in[6];
    const float* i_w = (const float*)d_in[7];
    const float* i_b = (const float*)d_in[8];
    const float* o_w = (const float*)d_in[9];
    const float* o_b = (const float*)d_in[10];
    float* out = (float*)d_out;
    char* ws = (char*)d_ws;

    const int B = 4, C = 512, N = 4096;
    const size_t NC = (size_t)N * C;
    const size_t W2 = (size_t)C * C;
    const size_t NN = (size_t)N * N;
    const int SMEM = 3 * SLOT;               // 147456 B dynamic LDS

    size_t off = 0;
    auto alloc = [&](size_t bytes) { size_t o = off; off += (bytes + 255) & ~(size_t)255; return o; };

    size_t o_meanC = alloc((size_t)B * C * 4);
    size_t o_rstdC = alloc((size_t)B * C * 4);
    size_t o_meanS = alloc((size_t)B * C * 4);
    size_t o_rstdS = alloc((size_t)B * C * 4);
    size_t o_cwT = alloc(W2 * 2);
    size_t o_swT = alloc(W2 * 2);
    size_t o_iwT = alloc(W2 * 2);
    size_t o_ow  = alloc(W2 * 2);
    size_t o_G   = alloc(W2 * 2);
    size_t o_W   = alloc(W2 * 2);
    size_t o_v   = alloc((size_t)C * 4);
    size_t o_wu  = alloc((size_t)C * 4);
    size_t o_u   = alloc((size_t)B * N * 4);
    size_t o_cnT = alloc(B * NC * 2);
    size_t o_snT = alloc(B * NC * 2);
    size_t o_sRT = alloc(B * NC * 2);
    size_t o_sgT = alloc(B * NC * 2);
    size_t o_sW  = alloc(B * NC * 2);
    size_t o_P   = alloc(2 * NN * 2);        // PAIR logits/P f16 (67MB)
    size_t o_pt  = alloc(8 * NC * 2);        // pair split-K4 partials f16

    if (ws_size < off) {
        (void)hipMemsetAsync(d_out, 0, (size_t)out_size * 4, stream);
        return;
    }

    float* meanC = (float*)(ws + o_meanC);
    float* rstdC = (float*)(ws + o_rstdC);
    float* meanS = (float*)(ws + o_meanS);
    float* rstdS = (float*)(ws + o_rstdS);
    u16* cwT = (u16*)(ws + o_cwT);
    u16* swT = (u16*)(ws + o_swT);
    u16* iwT = (u16*)(ws + o_iwT);
    u16* ow  = (u16*)(ws + o_ow);
    u16* Gf  = (u16*)(ws + o_G);
    u16* Wf  = (u16*)(ws + o_W);
    float* vb = (float*)(ws + o_v);
    float* wu = (float*)(ws + o_wu);
    float* ub = (float*)(ws + o_u);
    u16* cnT = (u16*)(ws + o_cnT);
    u16* snT = (u16*)(ws + o_snT);
    u16* sRT = (u16*)(ws + o_sRT);
    u16* sgT = (u16*)(ws + o_sgT);
    u16* sW  = (u16*)(ws + o_sW);
    u16* Pb  = (u16*)(ws + o_P);
    u16* partH = (u16*)(ws + o_pt);

    // 1) instance-norm stats
    stats_kernel<<<dim3(B * C, 2), 256, 0, stream>>>(c, s, meanC, rstdC, meanS, rstdS);
    // 2) fused packs
    packall<<<dim3(N / 32, C / 32, 8), dim3(32, 8), 0, stream>>>(
        c, s, meanC, rstdC, meanS, rstdS, cnT, snT, sRT);
    // 3) fused weight preps
    prep_kernel<<<dim3(16, 16, 4), dim3(32, 8), 0, stream>>>(
        c_w, s_w, i_w, o_w, cwT, swT, iwT, ow);
    bias_prep<<<dim3(4), 256, 0, stream>>>(o_w, i_b, o_b, s_w, c_b, vb, wu);
    // G[a,l] = c_w^T s_w  and  W[o,c] = o_w i_w  in one dispatch (M=N=512)
    gemm_bt<EPI_PLAIN_F16><<<dim3(4, 2, 2), 512, SMEM, stream>>>(
        cwT, swT, 512, 512, nullptr, nullptr, 0, nullptr, Gf, 512, 1,
        (long)(3 * W2), 0, (long)W2, 0, (long)W2);
    // 4) sgT[m,a] = sum_l snT[m,l]*G[a,l]  (M=4096, N=512)
    gemm_bt<EPI_PLAIN_F16><<<dim3(4, 16, B), 512, SMEM, stream>>>(
        snT, Gf, 512, 512, nullptr, nullptr, 0, nullptr, sgT, 512, 1,
        (long)NC, 0, 0, 0, (long)NC);
    // 5) sW[o,m] = sum_c W[o,c]*sRT[m,c]  (M=512, N=4096)
    gemm_bt<EPI_PLAIN_F16><<<dim3(32, 2, B), 512, SMEM, stream>>>(
        Wf, sRT, 512, 512, nullptr, nullptr, 0, nullptr, sW, 4096, 1,
        0, 0, (long)NC, 0, (long)NC);
    // 6) u[b,m] = sum_l snT[b,m,l]*wu[l]
    rowdot_kernel<<<dim3(B * N / 4), 256, 0, stream>>>(snT, wu, ub);
    // 7) attention in batch PAIRS
    for (int pb0 = 0; pb0 < B; pb0 += 2) {
        // logits: L[z,n,m] = cn.sg + u[m]  (M=N=4096, K=512; u fused as jb)
        gemm_bt<EPI_PLAIN_F16><<<dim3(32, 16, 2), 512, SMEM, stream>>>(
            cnT + (size_t)pb0 * NC, sgT + (size_t)pb0 * NC,
            512, 512, nullptr, ub + (size_t)pb0 * N, (long)N,
            nullptr, Pb, 4096, 1,
            (long)NC, 0, (long)NC, 0, (long)NN);
        // P = softmax_m(L) in place, 8192 rows
        softmax16<<<dim3(2 * N), 256, 0, stream>>>(Pb);
        // out_pre[o,n] = sum_m sW[o,m]*P[n,m]; split-K4, pair in one dispatch
        gemm_bt<EPI_PLAIN_F16><<<dim3(32, 2, 8), 512, SMEM, stream>>>(
            sW + (size_t)pb0 * NC, Pb, 1024, 4096, nullptr, nullptr, 0,
            nullptr, partH, 4096, 4,
            (long)NC, 1024L, (long)NN, 1024L, (long)NC);
        // out = sum partials + x + v
        reduce4resid<<<dim3((int)(NC / 2048), 2), 256, 0, stream>>>(
            partH, x + (size_t)pb0 * NC, vb, out + (size_t)pb0 * NC);
    }
}

// Round 15
// 395.692 us; speedup vs baseline: 1.1070x; 1.1070x over previous
//
#include <hip/hip_runtime.h>

typedef unsigned short u16;
typedef _Float16 f16x8 __attribute__((ext_vector_type(8)));
typedef float f32x4 __attribute__((ext_vector_type(4)));
typedef u16 u16x4 __attribute__((ext_vector_type(4)));
typedef u16 u16x8v __attribute__((ext_vector_type(8)));

__device__ __forceinline__ u16 f2h(float f) {
    _Float16 h = (_Float16)f;
    return __builtin_bit_cast(u16, h);
}
__device__ __forceinline__ float h2f(u16 u) {
    return (float)__builtin_bit_cast(_Float16, u);
}

// ---------------------------------------------------------------- stats ----
__global__ void __launch_bounds__(256) stats_kernel(
    const float* __restrict__ c, const float* __restrict__ s,
    float* __restrict__ mC, float* __restrict__ rC,
    float* __restrict__ mS, float* __restrict__ rS)
{
    const float* src = (blockIdx.y ? s : c) + (size_t)blockIdx.x * 4096;
    int t = threadIdx.x, lane = t & 63, wv = t >> 6;
    const float4* p = (const float4*)src;
    float sum = 0.f, sq = 0.f;
#pragma unroll
    for (int i = 0; i < 4; ++i) {
        float4 v = p[t + 256 * i];
        sum += v.x + v.y + v.z + v.w;
        sq  += v.x * v.x + v.y * v.y + v.z * v.z + v.w * v.w;
    }
#pragma unroll
    for (int m = 1; m < 64; m <<= 1) {
        sum += __shfl_xor(sum, m);
        sq  += __shfl_xor(sq, m);
    }
    __shared__ float sa[4], sb[4];
    if (!lane) { sa[wv] = sum; sb[wv] = sq; }
    __syncthreads();
    if (t == 0) {
        float S = sa[0] + sa[1] + sa[2] + sa[3];
        float Q = sb[0] + sb[1] + sb[2] + sb[3];
        float mean = S * (1.0f / 4096.0f);
        float var = (Q - 4096.0f * mean * mean) * (1.0f / 4095.0f);
        float rstd = rsqrtf(var + 1e-5f);
        if (blockIdx.y) { mS[blockIdx.x] = mean; rS[blockIdx.x] = rstd; }
        else            { mC[blockIdx.x] = mean; rC[blockIdx.x] = rstd; }
    }
}

// ------------------------------------------------- fused transpose pack ----
__global__ void __launch_bounds__(256) packall(
    const float* __restrict__ c, const float* __restrict__ s,
    const float* __restrict__ mC, const float* __restrict__ rC,
    const float* __restrict__ mS, const float* __restrict__ rS,
    u16* __restrict__ cnT, u16* __restrict__ snT, u16* __restrict__ sRT)
{
    __shared__ float tile[32][33];
    int z = blockIdx.z;
    bool isS = z >= 4;
    int b = isS ? z - 4 : z;
    const float* src  = isS ? s : c;
    const float* mean = isS ? mS : mC;
    const float* rstd = isS ? rS : rC;
    u16* dh = isS ? snT : cnT;
    int n0 = blockIdx.x * 32, c0 = blockIdx.y * 32;
    int tx = threadIdx.x, ty = threadIdx.y;
    const float* sbp = src + ((size_t)b * 512 + c0) * 4096 + n0;
#pragma unroll
    for (int it = 0; it < 4; ++it) {
        int cc = ty + it * 8;
        tile[cc][tx] = sbp[(size_t)cc * 4096 + tx];
    }
    __syncthreads();
    int ch = c0 + tx;
    float mn = mean[b * 512 + ch];
    float rs = rstd[b * 512 + ch];
    size_t obase = ((size_t)b * 4096 + n0) * 512 + c0;
#pragma unroll
    for (int it = 0; it < 4; ++it) {
        int r = ty + it * 8;
        float v = tile[tx][r];
        size_t o = obase + (size_t)r * 512 + tx;
        dh[o] = f2h((v - mn) * rs);
        if (isS) sRT[o] = f2h(v);
    }
}

// ------------------------------------------------- fused weight prep ------
__global__ void __launch_bounds__(256) prep_kernel(
    const float* __restrict__ c_w, const float* __restrict__ s_w,
    const float* __restrict__ i_w, const float* __restrict__ o_w,
    u16* __restrict__ cwT, u16* __restrict__ swT,
    u16* __restrict__ iwT, u16* __restrict__ ow)
{
    int z = blockIdx.z;
    int tx = threadIdx.x, ty = threadIdx.y;
    if (z == 3) {
        size_t base = ((size_t)(blockIdx.y * 16 + blockIdx.x) * 256 +
                       (ty * 32 + tx)) * 4;
        float4 v = *(const float4*)(o_w + base);
        u16x4 o;
        o[0] = f2h(v.x); o[1] = f2h(v.y); o[2] = f2h(v.z); o[3] = f2h(v.w);
        *(u16x4*)(ow + base) = o;
        return;
    }
    const float* w = (z == 0) ? c_w : (z == 1) ? s_w : i_w;
    u16* wT = (z == 0) ? cwT : (z == 1) ? swT : iwT;
    __shared__ float tile[32][33];
    int c0 = blockIdx.x * 32, k0 = blockIdx.y * 32;
#pragma unroll
    for (int it = 0; it < 4; ++it) {
        int kk = ty + it * 8;
        tile[kk][tx] = w[(size_t)(k0 + kk) * 512 + c0 + tx];
    }
    __syncthreads();
#pragma unroll
    for (int it = 0; it < 4; ++it) {
        int r = ty + it * 8;
        wT[(size_t)(c0 + r) * 512 + k0 + tx] = f2h(tile[tx][r]);
    }
}

// ------------------------------------------------- fused bias prep --------
__global__ void __launch_bounds__(256) bias_prep(
    const float* __restrict__ o_w, const float* __restrict__ i_b,
    const float* __restrict__ o_b, const float* __restrict__ s_w,
    const float* __restrict__ c_b, float* __restrict__ v,
    float* __restrict__ wu)
{
    __shared__ float buf[512];
    int t = threadIdx.x;
    bool isWu = blockIdx.x >= 2;
    const float* vec = isWu ? c_b : i_b;
    buf[t] = vec[t]; buf[t + 256] = vec[t + 256];
    __syncthreads();
    int o = (blockIdx.x & 1) * 256 + t;
    if (!isWu) {
        float acc = o_b[o];
        const float* row = o_w + (size_t)o * 512;
        for (int k = 0; k < 512; ++k) acc += row[k] * buf[k];
        v[o] = acc;
    } else {
        float acc = 0.f;
        for (int k = 0; k < 512; ++k) acc += buf[k] * s_w[(size_t)k * 512 + o];
        wu[o] = acc;
    }
}

// u[r] = sum_l snT[r,l] * wu[l]
__global__ void __launch_bounds__(256) rowdot_kernel(
    const u16* __restrict__ snT, const float* __restrict__ wu,
    float* __restrict__ u)
{
    __shared__ float swu[512];
    int t = threadIdx.x;
    swu[t] = wu[t]; swu[t + 256] = wu[t + 256];
    __syncthreads();
    int lane = t & 63, wv = t >> 6;
    int row = blockIdx.x * 4 + wv;
    u16x8v h = *(const u16x8v*)(snT + (size_t)row * 512 + lane * 8);
    float acc = 0.f;
#pragma unroll
    for (int i = 0; i < 8; ++i) acc += h2f(h[i]) * swu[lane * 8 + i];
#pragma unroll
    for (int m = 1; m < 64; m <<= 1) acc += __shfl_xor(acc, m);
    if (!lane) u[row] = acc;
}

// --------------------------------------------- GEMM (R12 2-phase engine) ----
// 256x128 tile, 512 threads (8 waves as 4M x 2N), BK=64, single-buffer.
#define EPI_F32       0
#define EPI_PLAIN_F16 2

__device__ __forceinline__ void stageA(
    const u16* __restrict__ g, int ldk, int i0, int k0, char* tile, int wv, int lane)
{
#pragma unroll
    for (int cc = 0; cc < 4; ++cc) {
        int chunk = (wv * 4 + cc) * 64 + lane;
        int row  = chunk >> 3;
        int slot = chunk & 7;
        int gc   = slot ^ (row & 7);
        const u16* gp = g + (size_t)(i0 + row) * ldk + (k0 + gc * 8);
        char* lp = tile + (size_t)(wv * 4 + cc) * 1024;
        __builtin_amdgcn_global_load_lds(
            (const __attribute__((address_space(1))) unsigned int*)gp,
            (__attribute__((address_space(3))) unsigned int*)lp, 16, 0, 0);
    }
}
__device__ __forceinline__ void stageB(
    const u16* __restrict__ g, int ldk, int j0, int k0, char* tile, int wv, int lane)
{
#pragma unroll
    for (int cc = 0; cc < 2; ++cc) {
        int chunk = (wv * 2 + cc) * 64 + lane;
        int row  = chunk >> 3;
        int slot = chunk & 7;
        int gc   = slot ^ (row & 7);
        const u16* gp = g + (size_t)(j0 + row) * ldk + (k0 + gc * 8);
        char* lp = tile + (size_t)(wv * 2 + cc) * 1024;
        __builtin_amdgcn_global_load_lds(
            (const __attribute__((address_space(1))) unsigned int*)gp,
            (__attribute__((address_space(3))) unsigned int*)lp, 16, 0, 0);
    }
}

template<int EPI>
__global__ void __launch_bounds__(512) gemm_bt(
    const u16* __restrict__ A_, const u16* __restrict__ B_,
    int K, int ldk, const float* __restrict__ bias,
    const float* __restrict__ jb, long jbZ,
    float* __restrict__ outF_, u16* __restrict__ outH_,
    int ldo, int zdiv,
    long aBatch, long aChunk, long bBatch, long bChunk, long oZ)
{
    __shared__ char smem[49152];                 // A: 32KB, B: 16KB

    int bz = blockIdx.z;
    int batch = bz / zdiv, chunk = bz % zdiv;
    const u16* A  = A_ + (size_t)batch * aBatch + (size_t)chunk * aChunk;
    const u16* Bm = B_ + (size_t)batch * bBatch + (size_t)chunk * bChunk;

    int i0 = blockIdx.y * 256, j0 = blockIdx.x * 128;
    int tid = threadIdx.x, lane = tid & 63, wv = tid >> 6;
    int wr = wv >> 1, wc = wv & 1;
    int r15 = lane & 15, h4 = lane >> 4;

    f32x4 zero = {0.f, 0.f, 0.f, 0.f};
    f32x4 acc[4][4];
#pragma unroll
    for (int m = 0; m < 4; ++m)
#pragma unroll
        for (int n = 0; n < 4; ++n) acc[m][n] = zero;

    for (int k0 = 0; k0 < K; k0 += 64) {
        stageA(A, ldk, i0, k0, smem, wv, lane);
        stageB(Bm, ldk, j0, k0, smem + 32768, wv, lane);
        asm volatile("s_waitcnt vmcnt(0)" ::: "memory");
        __syncthreads();
#pragma unroll
        for (int ks = 0; ks < 2; ++ks) {
            f16x8 a[4], b[4];
#pragma unroll
            for (int m = 0; m < 4; ++m) {
                int row = wr * 64 + m * 16 + r15;
                int off = row * 128 + (((ks * 4 + h4) ^ (row & 7)) << 4);
                a[m] = *(const f16x8*)(smem + off);
            }
#pragma unroll
            for (int n = 0; n < 4; ++n) {
                int col = wc * 64 + n * 16 + r15;
                int off = col * 128 + (((ks * 4 + h4) ^ (col & 7)) << 4);
                b[n] = *(const f16x8*)(smem + 32768 + off);
            }
#pragma unroll
            for (int m = 0; m < 4; ++m)
#pragma unroll
                for (int n = 0; n < 4; ++n)
                    acc[m][n] = __builtin_amdgcn_mfma_f32_16x16x32_f16(a[m], b[n], acc[m][n], 0, 0, 0);
        }
        __syncthreads();
    }

    float* outF = outF_ ? outF_ + (size_t)bz * oZ : nullptr;
    u16* outH = outH_ ? outH_ + (size_t)bz * oZ : nullptr;
    const float* jbp = jb ? jb + (size_t)bz * jbZ : nullptr;

#pragma unroll
    for (int m = 0; m < 4; ++m)
#pragma unroll
        for (int n = 0; n < 4; ++n) {
            int ibase = i0 + wr * 64 + m * 16 + h4 * 4;
            int j = j0 + wc * 64 + n * 16 + r15;
#pragma unroll
            for (int r = 0; r < 4; ++r) {
                int i = ibase + r;
                float v = acc[m][n][r];
                if constexpr (EPI == EPI_PLAIN_F16) {
                    if (bias) v += bias[i];
                    if (jbp) v += jbp[j];
                    outH[(size_t)i * ldo + j] = f2h(v);
                } else {
                    outF[(size_t)i * ldo + j] = v;
                }
            }
        }
}

// --------------------------------------- GEMM 8-phase 256^2 (logits / PV) ----
// BM=BN=256, BK=64, 512 thr, 8 waves. Per K-tile: 4 phases, each = one
// 128x128 C-quadrant over K=64 (wave w: rows (w>>2)*64, cols (w&3)*32).
// Halves staged 1/phase in order [A0,B0,B1,A1] into the alternate buffer;
// counted vmcnt (never 0 in steady state) keeps 3 halves in flight across
// raw s_barriers. RACE FIX (R15): every raw s_barrier is paired with an
// empty asm memory clobber so the compiler cannot hoist LDS reads above
// the opening barrier or sink them below the closing one (s_barrier alone
// has NO memory semantics at IR level — ERRATA #18 family).
__device__ __forceinline__ void stageHalf8(
    const u16* __restrict__ g, int ldk, int row0, int k0, char* dst,
    int wv, int lane)
{
#pragma unroll
    for (int cc = 0; cc < 2; ++cc) {
        int chunk = wv * 64 + lane + cc * 512;   // 1024 chunks = 128 rows x 128B
        int row  = chunk >> 3;
        int slot = chunk & 7;
        int gc   = slot ^ (row & 7);
        const u16* gp = g + (size_t)(row0 + row) * ldk + (k0 + gc * 8);
        char* lp = dst + (size_t)(wv * 64 + cc * 512) * 16;
        __builtin_amdgcn_global_load_lds(
            (const __attribute__((address_space(1))) unsigned int*)gp,
            (__attribute__((address_space(3))) unsigned int*)lp, 16, 0, 0);
    }
}

__global__ void __launch_bounds__(512) gemm8p(
    const u16* __restrict__ A_, const u16* __restrict__ B_,
    int K, int ldk, const float* __restrict__ bias,
    const float* __restrict__ jb, long jbZ,
    u16* __restrict__ outH_, int ldo, int zdiv,
    long aBatch, long aChunk, long bBatch, long bChunk, long oZ)
{
    extern __shared__ char smem[];               // 2 x (A 32KB | B 32KB)

    int bz = blockIdx.z;
    int batch = bz / zdiv, chunk = bz % zdiv;
    const u16* A  = A_ + (size_t)batch * aBatch + (size_t)chunk * aChunk;
    const u16* Bm = B_ + (size_t)batch * bBatch + (size_t)chunk * bChunk;

    int i0 = blockIdx.y * 256, j0 = blockIdx.x * 256;
    int tid = threadIdx.x, lane = tid & 63, wv = tid >> 6;
    int wr = wv >> 2, wc2 = wv & 3;              // quadrant split: 2M x 4N
    int r15 = lane & 15, h4 = lane >> 4;

    f32x4 zero = {0.f, 0.f, 0.f, 0.f};
    f32x4 acc[4][4][2];                          // [quadrant][m][n]
#pragma unroll
    for (int q = 0; q < 4; ++q)
#pragma unroll
        for (int m = 0; m < 4; ++m)
#pragma unroll
            for (int n = 0; n < 2; ++n) acc[q][m][n] = zero;

    int nk = K >> 6;
    // prologue: all 4 halves of tile 0 (order A0,B0,B1,A1)
    stageHalf8(A,  ldk, i0,       0, smem,                 wv, lane);
    stageHalf8(Bm, ldk, j0,       0, smem + 32768,         wv, lane);
    stageHalf8(Bm, ldk, j0 + 128, 0, smem + 32768 + 16384, wv, lane);
    stageHalf8(A,  ldk, i0 + 128, 0, smem + 16384,         wv, lane);
    asm volatile("s_waitcnt vmcnt(0)" ::: "memory");
    __builtin_amdgcn_s_barrier();
    asm volatile("" ::: "memory");

    for (int t = 0; t < nk; ++t) {
        char* bufA = smem + (t & 1) * 65536;
        char* bufB = bufA + 32768;
        char* nbuf = smem + ((t + 1) & 1) * 65536;
#pragma unroll
        for (int q = 0; q < 4; ++q) {
            const int mi = (q >= 2) ? 1 : 0;             // quad: (0,0)(0,1)(1,1)(1,0)
            const int ni = (q == 1 || q == 2) ? 1 : 0;
            if (t + 1 < nk) {
                // stage order: q0->A0, q1->B0, q2->B1, q3->A1 of tile t+1
                int k0 = (t + 1) * 64;
                if (q == 0)      stageHalf8(A,  ldk, i0,       k0, nbuf,                 wv, lane);
                else if (q == 1) stageHalf8(Bm, ldk, j0,       k0, nbuf + 32768,         wv, lane);
                else if (q == 2) stageHalf8(Bm, ldk, j0 + 128, k0, nbuf + 32768 + 16384, wv, lane);
                else             stageHalf8(A,  ldk, i0 + 128, k0, nbuf + 16384,         wv, lane);
                if (q < 3) asm volatile("s_waitcnt vmcnt(6)" ::: "memory");
            } else {
                if (q == 0)      asm volatile("s_waitcnt vmcnt(4)" ::: "memory");
                else if (q == 1) asm volatile("s_waitcnt vmcnt(2)" ::: "memory");
                else if (q == 2) asm volatile("s_waitcnt vmcnt(0)" ::: "memory");
            }
            __builtin_amdgcn_s_barrier();
            asm volatile("" ::: "memory");       // pin reads BELOW the barrier
            __builtin_amdgcn_sched_barrier(0);
            __builtin_amdgcn_s_setprio(1);
#pragma unroll
            for (int ks = 0; ks < 2; ++ks) {
                f16x8 a[4], b[2];
#pragma unroll
                for (int m = 0; m < 4; ++m) {
                    int row = mi * 128 + wr * 64 + m * 16 + r15;
                    int off = row * 128 + (((ks * 4 + h4) ^ (row & 7)) << 4);
                    a[m] = *(const f16x8*)(bufA + off);
                }
#pragma unroll
                for (int n = 0; n < 2; ++n) {
                    int col = ni * 128 + wc2 * 32 + n * 16 + r15;
                    int off = col * 128 + (((ks * 4 + h4) ^ (col & 7)) << 4);
                    b[n] = *(const f16x8*)(bufB + off);
                }
#pragma unroll
                for (int m = 0; m < 4; ++m)
#pragma unroll
                    for (int n = 0; n < 2; ++n)
                        acc[q][m][n] = __builtin_amdgcn_mfma_f32_16x16x32_f16(a[m], b[n], acc[q][m][n], 0, 0, 0);
            }
            __builtin_amdgcn_s_setprio(0);
            __builtin_amdgcn_sched_barrier(0);
            asm volatile("" ::: "memory");       // pin reads ABOVE the barrier
            __builtin_amdgcn_s_barrier();
        }
    }

    u16* outH = outH_ + (size_t)bz * oZ;
    const float* jbp = jb ? jb + (size_t)bz * jbZ : nullptr;
#pragma unroll
    for (int q = 0; q < 4; ++q) {
        const int mi = (q >= 2) ? 1 : 0;
        const int ni = (q == 1 || q == 2) ? 1 : 0;
#pragma unroll
        for (int m = 0; m < 4; ++m)
#pragma unroll
            for (int n = 0; n < 2; ++n) {
                int ibase = i0 + mi * 128 + wr * 64 + m * 16 + h4 * 4;
                int j = j0 + ni * 128 + wc2 * 32 + n * 16 + r15;
#pragma unroll
                for (int r = 0; r < 4; ++r) {
                    int i = ibase + r;
                    float v = acc[q][m][n][r];
                    if (bias) v += bias[i];
                    if (jbp) v += jbp[j];
                    outH[(size_t)i * ldo + j] = f2h(v);
                }
            }
    }
}

// ------------------------------------------------------ softmax (f16) ----
__global__ void __launch_bounds__(256) softmax16(u16* __restrict__ LP)
{
    u16x8v* row = (u16x8v*)(LP + (size_t)blockIdx.x * 4096);
    int t = threadIdx.x, lane = t & 63, wv = t >> 6;
    u16x8v ca = row[t], cb = row[t + 256];
    float va[8], vb[8];
    float mx = -3.4e38f;
#pragma unroll
    for (int i = 0; i < 8; ++i) {
        va[i] = h2f(ca[i]); vb[i] = h2f(cb[i]);
        mx = fmaxf(mx, fmaxf(va[i], vb[i]));
    }
#pragma unroll
    for (int m = 1; m < 64; m <<= 1) mx = fmaxf(mx, __shfl_xor(mx, m));
    __shared__ float sM[4], sS[4];
    if (!lane) sM[wv] = mx;
    __syncthreads();
    mx = fmaxf(fmaxf(sM[0], sM[1]), fmaxf(sM[2], sM[3]));
    float sum = 0.f;
#pragma unroll
    for (int i = 0; i < 8; ++i) {
        va[i] = __expf(va[i] - mx);
        vb[i] = __expf(vb[i] - mx);
        sum += va[i] + vb[i];
    }
#pragma unroll
    for (int m = 1; m < 64; m <<= 1) sum += __shfl_xor(sum, m);
    if (!lane) sS[wv] = sum;
    __syncthreads();
    sum = sS[0] + sS[1] + sS[2] + sS[3];
    float inv = 1.0f / sum;
    u16x8v oa, ob;
#pragma unroll
    for (int i = 0; i < 8; ++i) {
        oa[i] = f2h(va[i] * inv);
        ob[i] = f2h(vb[i] * inv);
    }
    row[t] = oa; row[t + 256] = ob;
}

// -------------------------------------- split-K reduce + residual + v -----
__global__ void __launch_bounds__(256) reduce4resid(
    const u16* __restrict__ part, const float* __restrict__ xr,
    const float* __restrict__ v, float* __restrict__ out)
{
    const size_t PLANE = 2097152;
    int b = blockIdx.y;
    size_t g8 = ((size_t)blockIdx.x * 256 + threadIdx.x) * 8;
    const u16* p0 = part + (size_t)b * 4 * PLANE + g8;
    float acc[8] = {0.f, 0.f, 0.f, 0.f, 0.f, 0.f, 0.f, 0.f};
#pragma unroll
    for (int k = 0; k < 4; ++k) {
        u16x8v h = *(const u16x8v*)(p0 + (size_t)k * PLANE);
#pragma unroll
        for (int i = 0; i < 8; ++i) acc[i] += h2f(h[i]);
    }
    const float4* xv = (const float4*)(xr + (size_t)b * PLANE + g8);
    float4 x0 = xv[0], x1 = xv[1];
    float vc = v[g8 >> 12];
    float4 o0, o1;
    o0.x = acc[0] + x0.x + vc; o0.y = acc[1] + x0.y + vc;
    o0.z = acc[2] + x0.z + vc; o0.w = acc[3] + x0.w + vc;
    o1.x = acc[4] + x1.x + vc; o1.y = acc[5] + x1.y + vc;
    o1.z = acc[6] + x1.z + vc; o1.w = acc[7] + x1.w + vc;
    float4* op = (float4*)(out + (size_t)b * PLANE + g8);
    op[0] = o0; op[1] = o1;
}

// -------------------------------------------------------------- launch ----
extern "C" void kernel_launch(void* const* d_in, const int* in_sizes, int n_in,
                              void* d_out, int out_size, void* d_ws, size_t ws_size,
                              hipStream_t stream)
{
    const float* c   = (const float*)d_in[0];
    const float* s   = (const float*)d_in[1];
    const float* x   = (const float*)d_in[2];
    const float* c_w = (const float*)d_in[3];
    const float* c_b = (const float*)d_in[4];
    const float* s_w = (const float*)d_in[5];
    const float* s_b = (const float*)d_in[6];
    const float* i_w = (const float*)d_in[7];
    const float* i_b = (const float*)d_in[8];
    const float* o_w = (const float*)d_in[9];
    const float* o_b = (const float*)d_in[10];
    float* out = (float*)d_out;
    char* ws = (char*)d_ws;

    const int B = 4, C = 512, N = 4096;
    const size_t NC = (size_t)N * C;
    const size_t W2 = (size_t)C * C;
    const size_t NN = (size_t)N * N;
    const int SMEM8 = 131072;                // 128KB dynamic LDS for gemm8p

    size_t off = 0;
    auto alloc = [&](size_t bytes) { size_t o = off; off += (bytes + 255) & ~(size_t)255; return o; };

    size_t o_meanC = alloc((size_t)B * C * 4);
    size_t o_rstdC = alloc((size_t)B * C * 4);
    size_t o_meanS = alloc((size_t)B * C * 4);
    size_t o_rstdS = alloc((size_t)B * C * 4);
    size_t o_cwT = alloc(W2 * 2);
    size_t o_swT = alloc(W2 * 2);
    size_t o_iwT = alloc(W2 * 2);
    size_t o_ow  = alloc(W2 * 2);
    size_t o_G   = alloc(W2 * 2);
    size_t o_W   = alloc(W2 * 2);
    size_t o_v   = alloc((size_t)C * 4);
    size_t o_wu  = alloc((size_t)C * 4);
    size_t o_u   = alloc((size_t)B * N * 4);
    size_t o_cnT = alloc(B * NC * 2);
    size_t o_snT = alloc(B * NC * 2);
    size_t o_sRT = alloc(B * NC * 2);
    size_t o_sgT = alloc(B * NC * 2);
    size_t o_sW  = alloc(B * NC * 2);
    size_t o_P   = alloc(2 * NN * 2);        // PAIR logits/P f16 (67MB)
    size_t o_pt  = alloc(8 * NC * 2);        // pair split-K4 partials f16

    if (ws_size < off) {
        (void)hipMemsetAsync(d_out, 0, (size_t)out_size * 4, stream);
        return;
    }

    float* meanC = (float*)(ws + o_meanC);
    float* rstdC = (float*)(ws + o_rstdC);
    float* meanS = (float*)(ws + o_meanS);
    float* rstdS = (float*)(ws + o_rstdS);
    u16* cwT = (u16*)(ws + o_cwT);
    u16* swT = (u16*)(ws + o_swT);
    u16* iwT = (u16*)(ws + o_iwT);
    u16* ow  = (u16*)(ws + o_ow);
    u16* Gf  = (u16*)(ws + o_G);
    u16* Wf  = (u16*)(ws + o_W);
    float* vb = (float*)(ws + o_v);
    float* wu = (float*)(ws + o_wu);
    float* ub = (float*)(ws + o_u);
    u16* cnT = (u16*)(ws + o_cnT);
    u16* snT = (u16*)(ws + o_snT);
    u16* sRT = (u16*)(ws + o_sRT);
    u16* sgT = (u16*)(ws + o_sgT);
    u16* sW  = (u16*)(ws + o_sW);
    u16* Pb  = (u16*)(ws + o_P);
    u16* partH = (u16*)(ws + o_pt);

    // 1) instance-norm stats
    stats_kernel<<<dim3(B * C, 2), 256, 0, stream>>>(c, s, meanC, rstdC, meanS, rstdS);
    // 2) fused packs
    packall<<<dim3(N / 32, C / 32, 8), dim3(32, 8), 0, stream>>>(
        c, s, meanC, rstdC, meanS, rstdS, cnT, snT, sRT);
    // 3) fused weight preps
    prep_kernel<<<dim3(16, 16, 4), dim3(32, 8), 0, stream>>>(
        c_w, s_w, i_w, o_w, cwT, swT, iwT, ow);
    bias_prep<<<dim3(4), 256, 0, stream>>>(o_w, i_b, o_b, s_w, c_b, vb, wu);
    // G and W in one dispatch (R12 engine)
    gemm_bt<EPI_PLAIN_F16><<<dim3(4, 2, 2), 512, 0, stream>>>(
        cwT, swT, 512, 512, nullptr, nullptr, 0, nullptr, Gf, 512, 1,
        (long)(3 * W2), 0, (long)W2, 0, (long)W2);
    // 4) sgT[m,a] = sum_l snT[m,l]*G[a,l]
    gemm_bt<EPI_PLAIN_F16><<<dim3(4, 16, B), 512, 0, stream>>>(
        snT, Gf, 512, 512, nullptr, nullptr, 0, nullptr, sgT, 512, 1,
        (long)NC, 0, 0, 0, (long)NC);
    // 5) sW[o,m] = sum_c W[o,c]*sRT[m,c]
    gemm_bt<EPI_PLAIN_F16><<<dim3(32, 2, B), 512, 0, stream>>>(
        Wf, sRT, 512, 512, nullptr, nullptr, 0, nullptr, sW, 4096, 1,
        0, 0, (long)NC, 0, (long)NC);
    // 6) u[b,m] = sum_l snT[b,m,l]*wu[l]
    rowdot_kernel<<<dim3(B * N / 4), 256, 0, stream>>>(snT, wu, ub);
    // 7) attention in batch PAIRS — 8-phase 256^2 engine for logits + PV
    for (int pb0 = 0; pb0 < B; pb0 += 2) {
        // logits: L[z,n,m] = cn.sg + u[m]  (M=N=4096, K=512)
        gemm8p<<<dim3(16, 16, 2), 512, SMEM8, stream>>>(
            cnT + (size_t)pb0 * NC, sgT + (size_t)pb0 * NC,
            512, 512, nullptr, ub + (size_t)pb0 * N, (long)N,
            Pb, 4096, 1,
            (long)NC, 0, (long)NC, 0, (long)NN);
        // P = softmax_m(L) in place, 8192 rows
        softmax16<<<dim3(2 * N), 256, 0, stream>>>(Pb);
        // out_pre[o,n] = sum_m sW[o,m]*P[n,m]; split-K4, pair in one dispatch
        gemm8p<<<dim3(16, 2, 8), 512, SMEM8, stream>>>(
            sW + (size_t)pb0 * NC, Pb, 1024, 4096, nullptr, nullptr, 0,
            partH, 4096, 4,
            (long)NC, 1024L, (long)NN, 1024L, (long)NC);
        // out = sum partials + x + v
        reduce4resid<<<dim3((int)(NC / 2048), 2), 256, 0, stream>>>(
            partH, x + (size_t)pb0 * NC, vb, out + (size_t)pb0 * NC);
    }
}

// Round 17
// 384.926 us; speedup vs baseline: 1.1380x; 1.0280x over previous
//
#include <hip/hip_runtime.h>

typedef unsigned short u16;
typedef _Float16 f16x8 __attribute__((ext_vector_type(8)));
typedef float f32x4 __attribute__((ext_vector_type(4)));
typedef u16 u16x4 __attribute__((ext_vector_type(4)));
typedef u16 u16x8v __attribute__((ext_vector_type(8)));

__device__ __forceinline__ u16 f2h(float f) {
    _Float16 h = (_Float16)f;
    return __builtin_bit_cast(u16, h);
}
__device__ __forceinline__ float h2f(u16 u) {
    return (float)__builtin_bit_cast(_Float16, u);
}

// ---------------------------------------------------------------- stats ----
__global__ void __launch_bounds__(256) stats_kernel(
    const float* __restrict__ c, const float* __restrict__ s,
    float* __restrict__ mC, float* __restrict__ rC,
    float* __restrict__ mS, float* __restrict__ rS)
{
    const float* src = (blockIdx.y ? s : c) + (size_t)blockIdx.x * 4096;
    int t = threadIdx.x, lane = t & 63, wv = t >> 6;
    const float4* p = (const float4*)src;
    float sum = 0.f, sq = 0.f;
#pragma unroll
    for (int i = 0; i < 4; ++i) {
        float4 v = p[t + 256 * i];
        sum += v.x + v.y + v.z + v.w;
        sq  += v.x * v.x + v.y * v.y + v.z * v.z + v.w * v.w;
    }
#pragma unroll
    for (int m = 1; m < 64; m <<= 1) {
        sum += __shfl_xor(sum, m);
        sq  += __shfl_xor(sq, m);
    }
    __shared__ float sa[4], sb[4];
    if (!lane) { sa[wv] = sum; sb[wv] = sq; }
    __syncthreads();
    if (t == 0) {
        float S = sa[0] + sa[1] + sa[2] + sa[3];
        float Q = sb[0] + sb[1] + sb[2] + sb[3];
        float mean = S * (1.0f / 4096.0f);
        float var = (Q - 4096.0f * mean * mean) * (1.0f / 4095.0f);
        float rstd = rsqrtf(var + 1e-5f);
        if (blockIdx.y) { mS[blockIdx.x] = mean; rS[blockIdx.x] = rstd; }
        else            { mC[blockIdx.x] = mean; rC[blockIdx.x] = rstd; }
    }
}

// ------------------------------------------------- fused transpose pack ----
__global__ void __launch_bounds__(256) packall(
    const float* __restrict__ c, const float* __restrict__ s,
    const float* __restrict__ mC, const float* __restrict__ rC,
    const float* __restrict__ mS, const float* __restrict__ rS,
    u16* __restrict__ cnT, u16* __restrict__ snT, u16* __restrict__ sRT)
{
    __shared__ float tile[32][33];
    int z = blockIdx.z;
    bool isS = z >= 4;
    int b = isS ? z - 4 : z;
    const float* src  = isS ? s : c;
    const float* mean = isS ? mS : mC;
    const float* rstd = isS ? rS : rC;
    u16* dh = isS ? snT : cnT;
    int n0 = blockIdx.x * 32, c0 = blockIdx.y * 32;
    int tx = threadIdx.x, ty = threadIdx.y;
    const float* sbp = src + ((size_t)b * 512 + c0) * 4096 + n0;
#pragma unroll
    for (int it = 0; it < 4; ++it) {
        int cc = ty + it * 8;
        tile[cc][tx] = sbp[(size_t)cc * 4096 + tx];
    }
    __syncthreads();
    int ch = c0 + tx;
    float mn = mean[b * 512 + ch];
    float rs = rstd[b * 512 + ch];
    size_t obase = ((size_t)b * 4096 + n0) * 512 + c0;
#pragma unroll
    for (int it = 0; it < 4; ++it) {
        int r = ty + it * 8;
        float v = tile[tx][r];
        size_t o = obase + (size_t)r * 512 + tx;
        dh[o] = f2h((v - mn) * rs);
        if (isS) sRT[o] = f2h(v);
    }
}

// ------------------------------------------------- fused weight prep ------
__global__ void __launch_bounds__(256) prep_kernel(
    const float* __restrict__ c_w, const float* __restrict__ s_w,
    const float* __restrict__ i_w, const float* __restrict__ o_w,
    u16* __restrict__ cwT, u16* __restrict__ swT,
    u16* __restrict__ iwT, u16* __restrict__ ow)
{
    int z = blockIdx.z;
    int tx = threadIdx.x, ty = threadIdx.y;
    if (z == 3) {
        size_t base = ((size_t)(blockIdx.y * 16 + blockIdx.x) * 256 +
                       (ty * 32 + tx)) * 4;
        float4 v = *(const float4*)(o_w + base);
        u16x4 o;
        o[0] = f2h(v.x); o[1] = f2h(v.y); o[2] = f2h(v.z); o[3] = f2h(v.w);
        *(u16x4*)(ow + base) = o;
        return;
    }
    const float* w = (z == 0) ? c_w : (z == 1) ? s_w : i_w;
    u16* wT = (z == 0) ? cwT : (z == 1) ? swT : iwT;
    __shared__ float tile[32][33];
    int c0 = blockIdx.x * 32, k0 = blockIdx.y * 32;
#pragma unroll
    for (int it = 0; it < 4; ++it) {
        int kk = ty + it * 8;
        tile[kk][tx] = w[(size_t)(k0 + kk) * 512 + c0 + tx];
    }
    __syncthreads();
#pragma unroll
    for (int it = 0; it < 4; ++it) {
        int r = ty + it * 8;
        wT[(size_t)(c0 + r) * 512 + k0 + tx] = f2h(tile[tx][r]);
    }
}

// ------------------------------------------------- fused bias prep --------
__global__ void __launch_bounds__(256) bias_prep(
    const float* __restrict__ o_w, const float* __restrict__ i_b,
    const float* __restrict__ o_b, const float* __restrict__ s_w,
    const float* __restrict__ c_b, float* __restrict__ v,
    float* __restrict__ wu)
{
    __shared__ float buf[512];
    int t = threadIdx.x;
    bool isWu = blockIdx.x >= 2;
    const float* vec = isWu ? c_b : i_b;
    buf[t] = vec[t]; buf[t + 256] = vec[t + 256];
    __syncthreads();
    int o = (blockIdx.x & 1) * 256 + t;
    if (!isWu) {
        float acc = o_b[o];
        const float* row = o_w + (size_t)o * 512;
        for (int k = 0; k < 512; ++k) acc += row[k] * buf[k];
        v[o] = acc;
    } else {
        float acc = 0.f;
        for (int k = 0; k < 512; ++k) acc += buf[k] * s_w[(size_t)k * 512 + o];
        wu[o] = acc;
    }
}

// u[r] = sum_l snT[r,l] * wu[l]
__global__ void __launch_bounds__(256) rowdot_kernel(
    const u16* __restrict__ snT, const float* __restrict__ wu,
    float* __restrict__ u)
{
    __shared__ float swu[512];
    int t = threadIdx.x;
    swu[t] = wu[t]; swu[t + 256] = wu[t + 256];
    __syncthreads();
    int lane = t & 63, wv = t >> 6;
    int row = blockIdx.x * 4 + wv;
    u16x8v h = *(const u16x8v*)(snT + (size_t)row * 512 + lane * 8);
    float acc = 0.f;
#pragma unroll
    for (int i = 0; i < 8; ++i) acc += h2f(h[i]) * swu[lane * 8 + i];
#pragma unroll
    for (int m = 1; m < 64; m <<= 1) acc += __shfl_xor(acc, m);
    if (!lane) u[row] = acc;
}

// --------------------------------------------- GEMM (R12 2-phase engine) ----
// 256x128 tile, 512 threads (8 waves as 4M x 2N), BK=64, single-buffer.
#define EPI_F32       0
#define EPI_PLAIN_F16 2

__device__ __forceinline__ void stageA(
    const u16* __restrict__ g, int ldk, int i0, int k0, char* tile, int wv, int lane)
{
#pragma unroll
    for (int cc = 0; cc < 4; ++cc) {
        int chunk = (wv * 4 + cc) * 64 + lane;
        int row  = chunk >> 3;
        int slot = chunk & 7;
        int gc   = slot ^ (row & 7);
        const u16* gp = g + (size_t)(i0 + row) * ldk + (k0 + gc * 8);
        char* lp = tile + (size_t)(wv * 4 + cc) * 1024;
        __builtin_amdgcn_global_load_lds(
            (const __attribute__((address_space(1))) unsigned int*)gp,
            (__attribute__((address_space(3))) unsigned int*)lp, 16, 0, 0);
    }
}
__device__ __forceinline__ void stageB(
    const u16* __restrict__ g, int ldk, int j0, int k0, char* tile, int wv, int lane)
{
#pragma unroll
    for (int cc = 0; cc < 2; ++cc) {
        int chunk = (wv * 2 + cc) * 64 + lane;
        int row  = chunk >> 3;
        int slot = chunk & 7;
        int gc   = slot ^ (row & 7);
        const u16* gp = g + (size_t)(j0 + row) * ldk + (k0 + gc * 8);
        char* lp = tile + (size_t)(wv * 2 + cc) * 1024;
        __builtin_amdgcn_global_load_lds(
            (const __attribute__((address_space(1))) unsigned int*)gp,
            (__attribute__((address_space(3))) unsigned int*)lp, 16, 0, 0);
    }
}

template<int EPI>
__global__ void __launch_bounds__(512) gemm_bt(
    const u16* __restrict__ A_, const u16* __restrict__ B_,
    int K, int ldk, const float* __restrict__ bias,
    const float* __restrict__ jb, long jbZ,
    float* __restrict__ outF_, u16* __restrict__ outH_,
    int ldo, int zdiv,
    long aBatch, long aChunk, long bBatch, long bChunk, long oZ)
{
    __shared__ char smem[49152];                 // A: 32KB, B: 16KB

    int bz = blockIdx.z;
    int batch = bz / zdiv, chunk = bz % zdiv;
    const u16* A  = A_ + (size_t)batch * aBatch + (size_t)chunk * aChunk;
    const u16* Bm = B_ + (size_t)batch * bBatch + (size_t)chunk * bChunk;

    int i0 = blockIdx.y * 256, j0 = blockIdx.x * 128;
    int tid = threadIdx.x, lane = tid & 63, wv = tid >> 6;
    int wr = wv >> 1, wc = wv & 1;
    int r15 = lane & 15, h4 = lane >> 4;

    f32x4 zero = {0.f, 0.f, 0.f, 0.f};
    f32x4 acc[4][4];
#pragma unroll
    for (int m = 0; m < 4; ++m)
#pragma unroll
        for (int n = 0; n < 4; ++n) acc[m][n] = zero;

    for (int k0 = 0; k0 < K; k0 += 64) {
        stageA(A, ldk, i0, k0, smem, wv, lane);
        stageB(Bm, ldk, j0, k0, smem + 32768, wv, lane);
        asm volatile("s_waitcnt vmcnt(0)" ::: "memory");
        __syncthreads();
#pragma unroll
        for (int ks = 0; ks < 2; ++ks) {
            f16x8 a[4], b[4];
#pragma unroll
            for (int m = 0; m < 4; ++m) {
                int row = wr * 64 + m * 16 + r15;
                int off = row * 128 + (((ks * 4 + h4) ^ (row & 7)) << 4);
                a[m] = *(const f16x8*)(smem + off);
            }
#pragma unroll
            for (int n = 0; n < 4; ++n) {
                int col = wc * 64 + n * 16 + r15;
                int off = col * 128 + (((ks * 4 + h4) ^ (col & 7)) << 4);
                b[n] = *(const f16x8*)(smem + 32768 + off);
            }
#pragma unroll
            for (int m = 0; m < 4; ++m)
#pragma unroll
                for (int n = 0; n < 4; ++n)
                    acc[m][n] = __builtin_amdgcn_mfma_f32_16x16x32_f16(a[m], b[n], acc[m][n], 0, 0, 0);
        }
        __syncthreads();
    }

    float* outF = outF_ ? outF_ + (size_t)bz * oZ : nullptr;
    u16* outH = outH_ ? outH_ + (size_t)bz * oZ : nullptr;
    const float* jbp = jb ? jb + (size_t)bz * jbZ : nullptr;

#pragma unroll
    for (int m = 0; m < 4; ++m)
#pragma unroll
        for (int n = 0; n < 4; ++n) {
            int ibase = i0 + wr * 64 + m * 16 + h4 * 4;
            int j = j0 + wc * 64 + n * 16 + r15;
#pragma unroll
            for (int r = 0; r < 4; ++r) {
                int i = ibase + r;
                float v = acc[m][n][r];
                if constexpr (EPI == EPI_PLAIN_F16) {
                    if (bias) v += bias[i];
                    if (jbp) v += jbp[j];
                    outH[(size_t)i * ldo + j] = f2h(v);
                } else {
                    outF[(size_t)i * ldo + j] = v;
                }
            }
        }
}

// --------------------------- GEMM 8-phase v2b (256^2, logits only) ---------
// BM=BN=256, BK=64, 512 thr (8 waves: wr=wv>>2 in 2M, wc2=wv&3 in 4N).
// Per K-tile: 4 phases, one 128x128 C-quadrant each (16 MFMA/wave/phase).
// One raw s_barrier per phase; stage of next tile's half issued AFTER the
// phase's MFMA; counted vmcnt(4) steady (tail 4/2/0); asm fences pin LDS
// reads inside their phase; no sched_barrier. R17 FIX: PHASE8 receives the
// BASE A/B buffers and MI/NI select the half inside the macro (R16 passed
// half-pointers AND kept MI/NI -> double offset, read garbage).
#define PHASE8(BUFA, BUFB, MI, NI, Q) do {                                   \
    __builtin_amdgcn_s_setprio(1);                                           \
    _Pragma("unroll")                                                        \
    for (int ks = 0; ks < 2; ++ks) {                                         \
        f16x8 a[4], b[2];                                                    \
        _Pragma("unroll")                                                    \
        for (int m = 0; m < 4; ++m) {                                        \
            int row = (MI) * 128 + wr * 64 + m * 16 + r15;                   \
            int off = row * 128 + (((ks * 4 + h4) ^ (row & 7)) << 4);        \
            a[m] = *(const f16x8*)((BUFA) + off);                            \
        }                                                                    \
        _Pragma("unroll")                                                    \
        for (int n = 0; n < 2; ++n) {                                        \
            int col = (NI) * 128 + wc2 * 32 + n * 16 + r15;                  \
            int off = col * 128 + (((ks * 4 + h4) ^ (col & 7)) << 4);        \
            b[n] = *(const f16x8*)((BUFB) + off);                            \
        }                                                                    \
        _Pragma("unroll")                                                    \
        for (int m = 0; m < 4; ++m)                                          \
            _Pragma("unroll")                                                \
            for (int n = 0; n < 2; ++n)                                      \
                acc[Q][m][n] = __builtin_amdgcn_mfma_f32_16x16x32_f16(       \
                    a[m], b[n], acc[Q][m][n], 0, 0, 0);                      \
    }                                                                        \
    __builtin_amdgcn_s_setprio(0);                                           \
} while (0)

__device__ __forceinline__ void stageHalf8(
    const u16* __restrict__ g, int ldk, int row0, int k0, char* dst,
    int wv, int lane)
{
#pragma unroll
    for (int cc = 0; cc < 2; ++cc) {
        int chunk = wv * 64 + lane + cc * 512;   // 1024 chunks = 128 rows x 128B
        int row  = chunk >> 3;
        int slot = chunk & 7;
        int gc   = slot ^ (row & 7);
        const u16* gp = g + (size_t)(row0 + row) * ldk + (k0 + gc * 8);
        char* lp = dst + (size_t)(wv * 64 + cc * 512) * 16;  // wave-uniform base
        __builtin_amdgcn_global_load_lds(
            (const __attribute__((address_space(1))) unsigned int*)gp,
            (__attribute__((address_space(3))) unsigned int*)lp, 16, 0, 0);
    }
}

__global__ void __launch_bounds__(512) gemm8p(
    const u16* __restrict__ A_, const u16* __restrict__ B_,
    int K, int ldk, const float* __restrict__ bias,
    const float* __restrict__ jb, long jbZ,
    u16* __restrict__ outH_, int ldo, int zdiv,
    long aBatch, long aChunk, long bBatch, long bChunk, long oZ)
{
    extern __shared__ char smem[];               // 2 x (A 32KB | B 32KB)

    int bz = blockIdx.z;
    int batch = bz / zdiv, chunk = bz % zdiv;
    const u16* A  = A_ + (size_t)batch * aBatch + (size_t)chunk * aChunk;
    const u16* Bm = B_ + (size_t)batch * bBatch + (size_t)chunk * bChunk;

    int i0 = blockIdx.y * 256, j0 = blockIdx.x * 256;
    int tid = threadIdx.x, lane = tid & 63, wv = tid >> 6;
    int wr = wv >> 2, wc2 = wv & 3;
    int r15 = lane & 15, h4 = lane >> 4;

    f32x4 zero = {0.f, 0.f, 0.f, 0.f};
    f32x4 acc[4][4][2];
#pragma unroll
    for (int q = 0; q < 4; ++q)
#pragma unroll
        for (int m = 0; m < 4; ++m)
#pragma unroll
            for (int n = 0; n < 2; ++n) acc[q][m][n] = zero;

    int nk = K >> 6;
    // prologue: 4 halves of tile 0, issue order A0,B0,B1,A1
    stageHalf8(A,  ldk, i0,       0, smem,         wv, lane);
    stageHalf8(Bm, ldk, j0,       0, smem + 32768, wv, lane);
    stageHalf8(Bm, ldk, j0 + 128, 0, smem + 49152, wv, lane);
    stageHalf8(A,  ldk, i0 + 128, 0, smem + 16384, wv, lane);

    for (int t = 0; t < nk; ++t) {
        char* buf  = smem + (t & 1) * 65536;
        char* bufB = buf + 32768;
        char* nbuf = smem + ((t + 1) & 1) * 65536;
        bool pre = (t + 1 < nk);
        int k1 = (t + 1) * 64;
        // ---- q0: needs A0,B0 of tile t ----
        asm volatile("s_waitcnt vmcnt(4)" ::: "memory");
        __builtin_amdgcn_s_barrier();
        asm volatile("" ::: "memory");
        PHASE8(buf, bufB, 0, 0, 0);
        if (pre) stageHalf8(A, ldk, i0, k1, nbuf, wv, lane);
        // ---- q1: needs B1 ----
        if (pre) { asm volatile("s_waitcnt vmcnt(4)" ::: "memory"); }
        else     { asm volatile("s_waitcnt vmcnt(2)" ::: "memory"); }
        __builtin_amdgcn_s_barrier();
        asm volatile("" ::: "memory");
        PHASE8(buf, bufB, 0, 1, 1);
        if (pre) stageHalf8(Bm, ldk, j0, k1, nbuf + 32768, wv, lane);
        // ---- q2: needs A1 ----
        if (pre) { asm volatile("s_waitcnt vmcnt(4)" ::: "memory"); }
        else     { asm volatile("s_waitcnt vmcnt(0)" ::: "memory"); }
        __builtin_amdgcn_s_barrier();
        asm volatile("" ::: "memory");
        PHASE8(buf, bufB, 1, 1, 2);
        if (pre) stageHalf8(Bm, ldk, j0 + 128, k1, nbuf + 49152, wv, lane);
        // ---- q3: needs nothing new ----
        asm volatile("" ::: "memory");
        __builtin_amdgcn_s_barrier();
        asm volatile("" ::: "memory");
        PHASE8(buf, bufB, 1, 0, 3);
        if (pre) stageHalf8(A, ldk, i0 + 128, k1, nbuf + 16384, wv, lane);
    }

    u16* outH = outH_ + (size_t)bz * oZ;
    const float* jbp = jb ? jb + (size_t)bz * jbZ : nullptr;
#pragma unroll
    for (int q = 0; q < 4; ++q) {
        const int mi = (q >= 2) ? 1 : 0;
        const int ni = (q == 1 || q == 2) ? 1 : 0;
#pragma unroll
        for (int m = 0; m < 4; ++m)
#pragma unroll
            for (int n = 0; n < 2; ++n) {
                int ibase = i0 + mi * 128 + wr * 64 + m * 16 + h4 * 4;
                int j = j0 + ni * 128 + wc2 * 32 + n * 16 + r15;
#pragma unroll
                for (int r = 0; r < 4; ++r) {
                    int i = ibase + r;
                    float v = acc[q][m][n][r];
                    if (bias) v += bias[i];
                    if (jbp) v += jbp[j];
                    outH[(size_t)i * ldo + j] = f2h(v);
                }
            }
    }
}

// ------------------------------------------------------ softmax (f16) ----
__global__ void __launch_bounds__(256) softmax16(u16* __restrict__ LP)
{
    u16x8v* row = (u16x8v*)(LP + (size_t)blockIdx.x * 4096);
    int t = threadIdx.x, lane = t & 63, wv = t >> 6;
    u16x8v ca = row[t], cb = row[t + 256];
    float va[8], vb[8];
    float mx = -3.4e38f;
#pragma unroll
    for (int i = 0; i < 8; ++i) {
        va[i] = h2f(ca[i]); vb[i] = h2f(cb[i]);
        mx = fmaxf(mx, fmaxf(va[i], vb[i]));
    }
#pragma unroll
    for (int m = 1; m < 64; m <<= 1) mx = fmaxf(mx, __shfl_xor(mx, m));
    __shared__ float sM[4], sS[4];
    if (!lane) sM[wv] = mx;
    __syncthreads();
    mx = fmaxf(fmaxf(sM[0], sM[1]), fmaxf(sM[2], sM[3]));
    float sum = 0.f;
#pragma unroll
    for (int i = 0; i < 8; ++i) {
        va[i] = __expf(va[i] - mx);
        vb[i] = __expf(vb[i] - mx);
        sum += va[i] + vb[i];
    }
#pragma unroll
    for (int m = 1; m < 64; m <<= 1) sum += __shfl_xor(sum, m);
    if (!lane) sS[wv] = sum;
    __syncthreads();
    sum = sS[0] + sS[1] + sS[2] + sS[3];
    float inv = 1.0f / sum;
    u16x8v oa, ob;
#pragma unroll
    for (int i = 0; i < 8; ++i) {
        oa[i] = f2h(va[i] * inv);
        ob[i] = f2h(vb[i] * inv);
    }
    row[t] = oa; row[t + 256] = ob;
}

// -------------------------------------- split-K reduce + residual + v -----
__global__ void __launch_bounds__(256) reduce4resid(
    const u16* __restrict__ part, const float* __restrict__ xr,
    const float* __restrict__ v, float* __restrict__ out)
{
    const size_t PLANE = 2097152;
    int b = blockIdx.y;
    size_t g8 = ((size_t)blockIdx.x * 256 + threadIdx.x) * 8;
    const u16* p0 = part + (size_t)b * 4 * PLANE + g8;
    float acc[8] = {0.f, 0.f, 0.f, 0.f, 0.f, 0.f, 0.f, 0.f};
#pragma unroll
    for (int k = 0; k < 4; ++k) {
        u16x8v h = *(const u16x8v*)(p0 + (size_t)k * PLANE);
#pragma unroll
        for (int i = 0; i < 8; ++i) acc[i] += h2f(h[i]);
    }
    const float4* xv = (const float4*)(xr + (size_t)b * PLANE + g8);
    float4 x0 = xv[0], x1 = xv[1];
    float vc = v[g8 >> 12];
    float4 o0, o1;
    o0.x = acc[0] + x0.x + vc; o0.y = acc[1] + x0.y + vc;
    o0.z = acc[2] + x0.z + vc; o0.w = acc[3] + x0.w + vc;
    o1.x = acc[4] + x1.x + vc; o1.y = acc[5] + x1.y + vc;
    o1.z = acc[6] + x1.z + vc; o1.w = acc[7] + x1.w + vc;
    float4* op = (float4*)(out + (size_t)b * PLANE + g8);
    op[0] = o0; op[1] = o1;
}

// -------------------------------------------------------------- launch ----
extern "C" void kernel_launch(void* const* d_in, const int* in_sizes, int n_in,
                              void* d_out, int out_size, void* d_ws, size_t ws_size,
                              hipStream_t stream)
{
    const float* c   = (const float*)d_in[0];
    const float* s   = (const float*)d_in[1];
    const float* x   = (const float*)d_in[2];
    const float* c_w = (const float*)d_in[3];
    const float* c_b = (const float*)d_in[4];
    const float* s_w = (const float*)d_in[5];
    const float* s_b = (const float*)d_in[6];
    const float* i_w = (const float*)d_in[7];
    const float* i_b = (const float*)d_in[8];
    const float* o_w = (const float*)d_in[9];
    const float* o_b = (const float*)d_in[10];
    float* out = (float*)d_out;
    char* ws = (char*)d_ws;

    const int B = 4, C = 512, N = 4096;
    const size_t NC = (size_t)N * C;
    const size_t W2 = (size_t)C * C;
    const size_t NN = (size_t)N * N;
    const int SMEM8 = 131072;                // 128KB dynamic LDS for gemm8p

    size_t off = 0;
    auto alloc = [&](size_t bytes) { size_t o = off; off += (bytes + 255) & ~(size_t)255; return o; };

    size_t o_meanC = alloc((size_t)B * C * 4);
    size_t o_rstdC = alloc((size_t)B * C * 4);
    size_t o_meanS = alloc((size_t)B * C * 4);
    size_t o_rstdS = alloc((size_t)B * C * 4);
    size_t o_cwT = alloc(W2 * 2);
    size_t o_swT = alloc(W2 * 2);
    size_t o_iwT = alloc(W2 * 2);
    size_t o_ow  = alloc(W2 * 2);
    size_t o_G   = alloc(W2 * 2);
    size_t o_W   = alloc(W2 * 2);
    size_t o_v   = alloc((size_t)C * 4);
    size_t o_wu  = alloc((size_t)C * 4);
    size_t o_u   = alloc((size_t)B * N * 4);
    size_t o_cnT = alloc(B * NC * 2);
    size_t o_snT = alloc(B * NC * 2);
    size_t o_sRT = alloc(B * NC * 2);
    size_t o_sgT = alloc(B * NC * 2);
    size_t o_sW  = alloc(B * NC * 2);
    size_t o_P   = alloc(2 * NN * 2);        // PAIR logits/P f16 (67MB)
    size_t o_pt  = alloc(8 * NC * 2);        // pair split-K4 partials f16

    if (ws_size < off) {
        (void)hipMemsetAsync(d_out, 0, (size_t)out_size * 4, stream);
        return;
    }

    float* meanC = (float*)(ws + o_meanC);
    float* rstdC = (float*)(ws + o_rstdC);
    float* meanS = (float*)(ws + o_meanS);
    float* rstdS = (float*)(ws + o_rstdS);
    u16* cwT = (u16*)(ws + o_cwT);
    u16* swT = (u16*)(ws + o_swT);
    u16* iwT = (u16*)(ws + o_iwT);
    u16* ow  = (u16*)(ws + o_ow);
    u16* Gf  = (u16*)(ws + o_G);
    u16* Wf  = (u16*)(ws + o_W);
    float* vb = (float*)(ws + o_v);
    float* wu = (float*)(ws + o_wu);
    float* ub = (float*)(ws + o_u);
    u16* cnT = (u16*)(ws + o_cnT);
    u16* snT = (u16*)(ws + o_snT);
    u16* sRT = (u16*)(ws + o_sRT);
    u16* sgT = (u16*)(ws + o_sgT);
    u16* sW  = (u16*)(ws + o_sW);
    u16* Pb  = (u16*)(ws + o_P);
    u16* partH = (u16*)(ws + o_pt);

    // 1) instance-norm stats
    stats_kernel<<<dim3(B * C, 2), 256, 0, stream>>>(c, s, meanC, rstdC, meanS, rstdS);
    // 2) fused packs
    packall<<<dim3(N / 32, C / 32, 8), dim3(32, 8), 0, stream>>>(
        c, s, meanC, rstdC, meanS, rstdS, cnT, snT, sRT);
    // 3) fused weight preps
    prep_kernel<<<dim3(16, 16, 4), dim3(32, 8), 0, stream>>>(
        c_w, s_w, i_w, o_w, cwT, swT, iwT, ow);
    bias_prep<<<dim3(4), 256, 0, stream>>>(o_w, i_b, o_b, s_w, c_b, vb, wu);
    // G and W in one dispatch (R12 engine)
    gemm_bt<EPI_PLAIN_F16><<<dim3(4, 2, 2), 512, 0, stream>>>(
        cwT, swT, 512, 512, nullptr, nullptr, 0, nullptr, Gf, 512, 1,
        (long)(3 * W2), 0, (long)W2, 0, (long)W2);
    // 4) sgT[m,a] = sum_l snT[m,l]*G[a,l]
    gemm_bt<EPI_PLAIN_F16><<<dim3(4, 16, B), 512, 0, stream>>>(
        snT, Gf, 512, 512, nullptr, nullptr, 0, nullptr, sgT, 512, 1,
        (long)NC, 0, 0, 0, (long)NC);
    // 5) sW[o,m] = sum_c W[o,c]*sRT[m,c]
    gemm_bt<EPI_PLAIN_F16><<<dim3(32, 2, B), 512, 0, stream>>>(
        Wf, sRT, 512, 512, nullptr, nullptr, 0, nullptr, sW, 4096, 1,
        0, 0, (long)NC, 0, (long)NC);
    // 6) u[b,m] = sum_l snT[b,m,l]*wu[l]
    rowdot_kernel<<<dim3(B * N / 4), 256, 0, stream>>>(snT, wu, ub);
    // 7) attention in batch PAIRS — 8-phase v2b for logits, R12 engine for PV
    for (int pb0 = 0; pb0 < B; pb0 += 2) {
        // logits: L[z,n,m] = cn.sg + u[m]  (M=N=4096, K=512)
        gemm8p<<<dim3(16, 16, 2), 512, SMEM8, stream>>>(
            cnT + (size_t)pb0 * NC, sgT + (size_t)pb0 * NC,
            512, 512, nullptr, ub + (size_t)pb0 * N, (long)N,
            Pb, 4096, 1,
            (long)NC, 0, (long)NC, 0, (long)NN);
        // P = softmax_m(L) in place, 8192 rows
        softmax16<<<dim3(2 * N), 256, 0, stream>>>(Pb);
        // out_pre[o,n] = sum_m sW[o,m]*P[n,m]; split-K4, pair in one dispatch
        gemm_bt<EPI_PLAIN_F16><<<dim3(32, 2, 8), 512, 0, stream>>>(
            sW + (size_t)pb0 * NC, Pb, 1024, 4096, nullptr, nullptr, 0,
            nullptr, partH, 4096, 4,
            (long)NC, 1024L, (long)NN, 1024L, (long)NC);
        // out = sum partials + x + v
        reduce4resid<<<dim3((int)(NC / 2048), 2), 256, 0, stream>>>(
            partH, x + (size_t)pb0 * NC, vb, out + (size_t)pb0 * NC);
    }
}

// Round 18
// 339.784 us; speedup vs baseline: 1.2891x; 1.1329x over previous
//
#include <hip/hip_runtime.h>

typedef unsigned short u16;
typedef _Float16 f16x8 __attribute__((ext_vector_type(8)));
typedef float f32x4 __attribute__((ext_vector_type(4)));
typedef u16 u16x4 __attribute__((ext_vector_type(4)));
typedef u16 u16x8v __attribute__((ext_vector_type(8)));

__device__ __forceinline__ u16 f2h(float f) {
    _Float16 h = (_Float16)f;
    return __builtin_bit_cast(u16, h);
}
__device__ __forceinline__ float h2f(u16 u) {
    return (float)__builtin_bit_cast(_Float16, u);
}

// ---------------------------------------------------------------- stats ----
__global__ void __launch_bounds__(256) stats_kernel(
    const float* __restrict__ c, const float* __restrict__ s,
    float* __restrict__ mC, float* __restrict__ rC,
    float* __restrict__ mS, float* __restrict__ rS)
{
    const float* src = (blockIdx.y ? s : c) + (size_t)blockIdx.x * 4096;
    int t = threadIdx.x, lane = t & 63, wv = t >> 6;
    const float4* p = (const float4*)src;
    float sum = 0.f, sq = 0.f;
#pragma unroll
    for (int i = 0; i < 4; ++i) {
        float4 v = p[t + 256 * i];
        sum += v.x + v.y + v.z + v.w;
        sq  += v.x * v.x + v.y * v.y + v.z * v.z + v.w * v.w;
    }
#pragma unroll
    for (int m = 1; m < 64; m <<= 1) {
        sum += __shfl_xor(sum, m);
        sq  += __shfl_xor(sq, m);
    }
    __shared__ float sa[4], sb[4];
    if (!lane) { sa[wv] = sum; sb[wv] = sq; }
    __syncthreads();
    if (t == 0) {
        float S = sa[0] + sa[1] + sa[2] + sa[3];
        float Q = sb[0] + sb[1] + sb[2] + sb[3];
        float mean = S * (1.0f / 4096.0f);
        float var = (Q - 4096.0f * mean * mean) * (1.0f / 4095.0f);
        float rstd = rsqrtf(var + 1e-5f);
        if (blockIdx.y) { mS[blockIdx.x] = mean; rS[blockIdx.x] = rstd; }
        else            { mC[blockIdx.x] = mean; rC[blockIdx.x] = rstd; }
    }
}

// ------------------------------------------------- fused transpose pack ----
__global__ void __launch_bounds__(256) packall(
    const float* __restrict__ c, const float* __restrict__ s,
    const float* __restrict__ mC, const float* __restrict__ rC,
    const float* __restrict__ mS, const float* __restrict__ rS,
    u16* __restrict__ cnT, u16* __restrict__ snT, u16* __restrict__ sRT)
{
    __shared__ float tile[32][33];
    int z = blockIdx.z;
    bool isS = z >= 4;
    int b = isS ? z - 4 : z;
    const float* src  = isS ? s : c;
    const float* mean = isS ? mS : mC;
    const float* rstd = isS ? rS : rC;
    u16* dh = isS ? snT : cnT;
    int n0 = blockIdx.x * 32, c0 = blockIdx.y * 32;
    int tx = threadIdx.x, ty = threadIdx.y;
    const float* sbp = src + ((size_t)b * 512 + c0) * 4096 + n0;
#pragma unroll
    for (int it = 0; it < 4; ++it) {
        int cc = ty + it * 8;
        tile[cc][tx] = sbp[(size_t)cc * 4096 + tx];
    }
    __syncthreads();
    int ch = c0 + tx;
    float mn = mean[b * 512 + ch];
    float rs = rstd[b * 512 + ch];
    size_t obase = ((size_t)b * 4096 + n0) * 512 + c0;
#pragma unroll
    for (int it = 0; it < 4; ++it) {
        int r = ty + it * 8;
        float v = tile[tx][r];
        size_t o = obase + (size_t)r * 512 + tx;
        dh[o] = f2h((v - mn) * rs);
        if (isS) sRT[o] = f2h(v);
    }
}

// ------------------------------------------------- fused weight prep ------
__global__ void __launch_bounds__(256) prep_kernel(
    const float* __restrict__ c_w, const float* __restrict__ s_w,
    const float* __restrict__ i_w, const float* __restrict__ o_w,
    u16* __restrict__ cwT, u16* __restrict__ swT,
    u16* __restrict__ iwT, u16* __restrict__ ow)
{
    int z = blockIdx.z;
    int tx = threadIdx.x, ty = threadIdx.y;
    if (z == 3) {
        size_t base = ((size_t)(blockIdx.y * 16 + blockIdx.x) * 256 +
                       (ty * 32 + tx)) * 4;
        float4 v = *(const float4*)(o_w + base);
        u16x4 o;
        o[0] = f2h(v.x); o[1] = f2h(v.y); o[2] = f2h(v.z); o[3] = f2h(v.w);
        *(u16x4*)(ow + base) = o;
        return;
    }
    const float* w = (z == 0) ? c_w : (z == 1) ? s_w : i_w;
    u16* wT = (z == 0) ? cwT : (z == 1) ? swT : iwT;
    __shared__ float tile[32][33];
    int c0 = blockIdx.x * 32, k0 = blockIdx.y * 32;
#pragma unroll
    for (int it = 0; it < 4; ++it) {
        int kk = ty + it * 8;
        tile[kk][tx] = w[(size_t)(k0 + kk) * 512 + c0 + tx];
    }
    __syncthreads();
#pragma unroll
    for (int it = 0; it < 4; ++it) {
        int r = ty + it * 8;
        wT[(size_t)(c0 + r) * 512 + k0 + tx] = f2h(tile[tx][r]);
    }
}

// ------------------------------------------------- fused bias prep --------
__global__ void __launch_bounds__(256) bias_prep(
    const float* __restrict__ o_w, const float* __restrict__ i_b,
    const float* __restrict__ o_b, const float* __restrict__ s_w,
    const float* __restrict__ c_b, float* __restrict__ v,
    float* __restrict__ wu)
{
    __shared__ float buf[512];
    int t = threadIdx.x;
    bool isWu = blockIdx.x >= 2;
    const float* vec = isWu ? c_b : i_b;
    buf[t] = vec[t]; buf[t + 256] = vec[t + 256];
    __syncthreads();
    int o = (blockIdx.x & 1) * 256 + t;
    if (!isWu) {
        float acc = o_b[o];
        const float* row = o_w + (size_t)o * 512;
        for (int k = 0; k < 512; ++k) acc += row[k] * buf[k];
        v[o] = acc;
    } else {
        float acc = 0.f;
        for (int k = 0; k < 512; ++k) acc += buf[k] * s_w[(size_t)k * 512 + o];
        wu[o] = acc;
    }
}

// u[r] = sum_l snT[r,l] * wu[l]
__global__ void __launch_bounds__(256) rowdot_kernel(
    const u16* __restrict__ snT, const float* __restrict__ wu,
    float* __restrict__ u)
{
    __shared__ float swu[512];
    int t = threadIdx.x;
    swu[t] = wu[t]; swu[t + 256] = wu[t + 256];
    __syncthreads();
    int lane = t & 63, wv = t >> 6;
    int row = blockIdx.x * 4 + wv;
    u16x8v h = *(const u16x8v*)(snT + (size_t)row * 512 + lane * 8);
    float acc = 0.f;
#pragma unroll
    for (int i = 0; i < 8; ++i) acc += h2f(h[i]) * swu[lane * 8 + i];
#pragma unroll
    for (int m = 1; m < 64; m <<= 1) acc += __shfl_xor(acc, m);
    if (!lane) u[row] = acc;
}

// --------------------------------------------- GEMM (R12 2-phase engine) ----
// 256x128 tile, 512 threads (8 waves as 4M x 2N), BK=64, single-buffer.
#define EPI_F32       0
#define EPI_PLAIN_F16 2

__device__ __forceinline__ void stageA(
    const u16* __restrict__ g, int ldk, int i0, int k0, char* tile, int wv, int lane)
{
#pragma unroll
    for (int cc = 0; cc < 4; ++cc) {
        int chunk = (wv * 4 + cc) * 64 + lane;
        int row  = chunk >> 3;
        int slot = chunk & 7;
        int gc   = slot ^ (row & 7);
        const u16* gp = g + (size_t)(i0 + row) * ldk + (k0 + gc * 8);
        char* lp = tile + (size_t)(wv * 4 + cc) * 1024;
        __builtin_amdgcn_global_load_lds(
            (const __attribute__((address_space(1))) unsigned int*)gp,
            (__attribute__((address_space(3))) unsigned int*)lp, 16, 0, 0);
    }
}
__device__ __forceinline__ void stageB(
    const u16* __restrict__ g, int ldk, int j0, int k0, char* tile, int wv, int lane)
{
#pragma unroll
    for (int cc = 0; cc < 2; ++cc) {
        int chunk = (wv * 2 + cc) * 64 + lane;
        int row  = chunk >> 3;
        int slot = chunk & 7;
        int gc   = slot ^ (row & 7);
        const u16* gp = g + (size_t)(j0 + row) * ldk + (k0 + gc * 8);
        char* lp = tile + (size_t)(wv * 2 + cc) * 1024;
        __builtin_amdgcn_global_load_lds(
            (const __attribute__((address_space(1))) unsigned int*)gp,
            (__attribute__((address_space(3))) unsigned int*)lp, 16, 0, 0);
    }
}

template<int EPI>
__global__ void __launch_bounds__(512) gemm_bt(
    const u16* __restrict__ A_, const u16* __restrict__ B_,
    int K, int ldk, const float* __restrict__ bias,
    const float* __restrict__ jb, long jbZ,
    float* __restrict__ outF_, u16* __restrict__ outH_,
    int ldo, int zdiv,
    long aBatch, long aChunk, long bBatch, long bChunk, long oZ)
{
    __shared__ char smem[49152];                 // A: 32KB, B: 16KB

    int bz = blockIdx.z;
    int batch = bz / zdiv, chunk = bz % zdiv;
    const u16* A  = A_ + (size_t)batch * aBatch + (size_t)chunk * aChunk;
    const u16* Bm = B_ + (size_t)batch * bBatch + (size_t)chunk * bChunk;

    int i0 = blockIdx.y * 256, j0 = blockIdx.x * 128;
    int tid = threadIdx.x, lane = tid & 63, wv = tid >> 6;
    int wr = wv >> 1, wc = wv & 1;
    int r15 = lane & 15, h4 = lane >> 4;

    f32x4 zero = {0.f, 0.f, 0.f, 0.f};
    f32x4 acc[4][4];
#pragma unroll
    for (int m = 0; m < 4; ++m)
#pragma unroll
        for (int n = 0; n < 4; ++n) acc[m][n] = zero;

    for (int k0 = 0; k0 < K; k0 += 64) {
        stageA(A, ldk, i0, k0, smem, wv, lane);
        stageB(Bm, ldk, j0, k0, smem + 32768, wv, lane);
        asm volatile("s_waitcnt vmcnt(0)" ::: "memory");
        __syncthreads();
#pragma unroll
        for (int ks = 0; ks < 2; ++ks) {
            f16x8 a[4], b[4];
#pragma unroll
            for (int m = 0; m < 4; ++m) {
                int row = wr * 64 + m * 16 + r15;
                int off = row * 128 + (((ks * 4 + h4) ^ (row & 7)) << 4);
                a[m] = *(const f16x8*)(smem + off);
            }
#pragma unroll
            for (int n = 0; n < 4; ++n) {
                int col = wc * 64 + n * 16 + r15;
                int off = col * 128 + (((ks * 4 + h4) ^ (col & 7)) << 4);
                b[n] = *(const f16x8*)(smem + 32768 + off);
            }
#pragma unroll
            for (int m = 0; m < 4; ++m)
#pragma unroll
                for (int n = 0; n < 4; ++n)
                    acc[m][n] = __builtin_amdgcn_mfma_f32_16x16x32_f16(a[m], b[n], acc[m][n], 0, 0, 0);
        }
        __syncthreads();
    }

    float* outF = outF_ ? outF_ + (size_t)bz * oZ : nullptr;
    u16* outH = outH_ ? outH_ + (size_t)bz * oZ : nullptr;
    const float* jbp = jb ? jb + (size_t)bz * jbZ : nullptr;

#pragma unroll
    for (int m = 0; m < 4; ++m)
#pragma unroll
        for (int n = 0; n < 4; ++n) {
            int ibase = i0 + wr * 64 + m * 16 + h4 * 4;
            int j = j0 + wc * 64 + n * 16 + r15;
#pragma unroll
            for (int r = 0; r < 4; ++r) {
                int i = ibase + r;
                float v = acc[m][n][r];
                if constexpr (EPI == EPI_PLAIN_F16) {
                    if (bias) v += bias[i];
                    if (jbp) v += jbp[j];
                    outH[(size_t)i * ldo + j] = f2h(v);
                } else {
                    outF[(size_t)i * ldo + j] = v;
                }
            }
        }
}

// ------------------------- logits GEMM, 256x256 tile, 2-phase --------------
// BM=BN=256, BK=64, 512 thr (8 waves as 2M x 4N, each 128x64 output).
// Same sync structure as gemm_bt (stage -> vmcnt(0) -> syncthreads ->
// MFMA -> syncthreads); only the tile geometry differs. K fixed 512,
// ldk fixed 512, ldo fixed 4096. jb = per-column bias u[m].
__device__ __forceinline__ void stage256(
    const u16* __restrict__ g, int r0, int k0, char* tile, int wv, int lane)
{
#pragma unroll
    for (int cc = 0; cc < 4; ++cc) {
        int grp = cc * 8 + wv;                   // 32 groups of 64 chunks
        int chunk = grp * 64 + lane;             // 0..2047 -> 256 rows x 128B
        int row  = chunk >> 3;
        int slot = chunk & 7;
        int gc   = slot ^ (row & 7);
        const u16* gp = g + (size_t)(r0 + row) * 512 + (k0 + gc * 8);
        char* lp = tile + (size_t)grp * 1024;    // wave-uniform base
        __builtin_amdgcn_global_load_lds(
            (const __attribute__((address_space(1))) unsigned int*)gp,
            (__attribute__((address_space(3))) unsigned int*)lp, 16, 0, 0);
    }
}

__global__ void __launch_bounds__(512) glogits256(
    const u16* __restrict__ A_, const u16* __restrict__ B_,
    const float* __restrict__ jb_, u16* __restrict__ outH_,
    long aZ, long bZ, long jbZ, long oZ)
{
    extern __shared__ char smem[];               // A 32KB | B 32KB

    int bz = blockIdx.z;
    const u16* A  = A_ + (size_t)bz * aZ;
    const u16* Bm = B_ + (size_t)bz * bZ;

    int i0 = blockIdx.y * 256, j0 = blockIdx.x * 256;
    int tid = threadIdx.x, lane = tid & 63, wv = tid >> 6;
    int wr = wv >> 2, wc = wv & 3;               // 2M x 4N waves, 128x64 each
    int r15 = lane & 15, h4 = lane >> 4;

    f32x4 zero = {0.f, 0.f, 0.f, 0.f};
    f32x4 acc[8][4];
#pragma unroll
    for (int m = 0; m < 8; ++m)
#pragma unroll
        for (int n = 0; n < 4; ++n) acc[m][n] = zero;

    for (int k0 = 0; k0 < 512; k0 += 64) {
        stage256(A,  i0, k0, smem,         wv, lane);
        stage256(Bm, j0, k0, smem + 32768, wv, lane);
        asm volatile("s_waitcnt vmcnt(0)" ::: "memory");
        __syncthreads();
#pragma unroll
        for (int ks = 0; ks < 2; ++ks) {
            f16x8 a[8], b[4];
#pragma unroll
            for (int m = 0; m < 8; ++m) {
                int row = wr * 128 + m * 16 + r15;
                int off = row * 128 + (((ks * 4 + h4) ^ (row & 7)) << 4);
                a[m] = *(const f16x8*)(smem + off);
            }
#pragma unroll
            for (int n = 0; n < 4; ++n) {
                int col = wc * 64 + n * 16 + r15;
                int off = col * 128 + (((ks * 4 + h4) ^ (col & 7)) << 4);
                b[n] = *(const f16x8*)(smem + 32768 + off);
            }
#pragma unroll
            for (int m = 0; m < 8; ++m)
#pragma unroll
                for (int n = 0; n < 4; ++n)
                    acc[m][n] = __builtin_amdgcn_mfma_f32_16x16x32_f16(a[m], b[n], acc[m][n], 0, 0, 0);
        }
        __syncthreads();
    }

    u16* outH = outH_ + (size_t)bz * oZ;
    const float* jbp = jb_ + (size_t)bz * jbZ;
#pragma unroll
    for (int m = 0; m < 8; ++m)
#pragma unroll
        for (int n = 0; n < 4; ++n) {
            int ibase = i0 + wr * 128 + m * 16 + h4 * 4;
            int j = j0 + wc * 64 + n * 16 + r15;
            float ub = jbp[j];
#pragma unroll
            for (int r = 0; r < 4; ++r) {
                int i = ibase + r;
                outH[(size_t)i * 4096 + j] = f2h(acc[m][n][r] + ub);
            }
        }
}

// ------------------------------------------------------ softmax (f16) ----
__global__ void __launch_bounds__(256) softmax16(u16* __restrict__ LP)
{
    u16x8v* row = (u16x8v*)(LP + (size_t)blockIdx.x * 4096);
    int t = threadIdx.x, lane = t & 63, wv = t >> 6;
    u16x8v ca = row[t], cb = row[t + 256];
    float va[8], vb[8];
    float mx = -3.4e38f;
#pragma unroll
    for (int i = 0; i < 8; ++i) {
        va[i] = h2f(ca[i]); vb[i] = h2f(cb[i]);
        mx = fmaxf(mx, fmaxf(va[i], vb[i]));
    }
#pragma unroll
    for (int m = 1; m < 64; m <<= 1) mx = fmaxf(mx, __shfl_xor(mx, m));
    __shared__ float sM[4], sS[4];
    if (!lane) sM[wv] = mx;
    __syncthreads();
    mx = fmaxf(fmaxf(sM[0], sM[1]), fmaxf(sM[2], sM[3]));
    float sum = 0.f;
#pragma unroll
    for (int i = 0; i < 8; ++i) {
        va[i] = __expf(va[i] - mx);
        vb[i] = __expf(vb[i] - mx);
        sum += va[i] + vb[i];
    }
#pragma unroll
    for (int m = 1; m < 64; m <<= 1) sum += __shfl_xor(sum, m);
    if (!lane) sS[wv] = sum;
    __syncthreads();
    sum = sS[0] + sS[1] + sS[2] + sS[3];
    float inv = 1.0f / sum;
    u16x8v oa, ob;
#pragma unroll
    for (int i = 0; i < 8; ++i) {
        oa[i] = f2h(va[i] * inv);
        ob[i] = f2h(vb[i] * inv);
    }
    row[t] = oa; row[t + 256] = ob;
}

// -------------------------------------- split-K reduce + residual + v -----
__global__ void __launch_bounds__(256) reduce4resid(
    const u16* __restrict__ part, const float* __restrict__ xr,
    const float* __restrict__ v, float* __restrict__ out)
{
    const size_t PLANE = 2097152;
    int b = blockIdx.y;
    size_t g8 = ((size_t)blockIdx.x * 256 + threadIdx.x) * 8;
    const u16* p0 = part + (size_t)b * 4 * PLANE + g8;
    float acc[8] = {0.f, 0.f, 0.f, 0.f, 0.f, 0.f, 0.f, 0.f};
#pragma unroll
    for (int k = 0; k < 4; ++k) {
        u16x8v h = *(const u16x8v*)(p0 + (size_t)k * PLANE);
#pragma unroll
        for (int i = 0; i < 8; ++i) acc[i] += h2f(h[i]);
    }
    const float4* xv = (const float4*)(xr + (size_t)b * PLANE + g8);
    float4 x0 = xv[0], x1 = xv[1];
    float vc = v[g8 >> 12];
    float4 o0, o1;
    o0.x = acc[0] + x0.x + vc; o0.y = acc[1] + x0.y + vc;
    o0.z = acc[2] + x0.z + vc; o0.w = acc[3] + x0.w + vc;
    o1.x = acc[4] + x1.x + vc; o1.y = acc[5] + x1.y + vc;
    o1.z = acc[6] + x1.z + vc; o1.w = acc[7] + x1.w + vc;
    float4* op = (float4*)(out + (size_t)b * PLANE + g8);
    op[0] = o0; op[1] = o1;
}

// -------------------------------------------------------------- launch ----
extern "C" void kernel_launch(void* const* d_in, const int* in_sizes, int n_in,
                              void* d_out, int out_size, void* d_ws, size_t ws_size,
                              hipStream_t stream)
{
    const float* c   = (const float*)d_in[0];
    const float* s   = (const float*)d_in[1];
    const float* x   = (const float*)d_in[2];
    const float* c_w = (const float*)d_in[3];
    const float* c_b = (const float*)d_in[4];
    const float* s_w = (const float*)d_in[5];
    const float* s_b = (const float*)d_in[6];
    const float* i_w = (const float*)d_in[7];
    const float* i_b = (const float*)d_in[8];
    const float* o_w = (const float*)d_in[9];
    const float* o_b = (const float*)d_in[10];
    float* out = (float*)d_out;
    char* ws = (char*)d_ws;

    const int B = 4, C = 512, N = 4096;
    const size_t NC = (size_t)N * C;
    const size_t W2 = (size_t)C * C;
    const size_t NN = (size_t)N * N;
    const int SMEM256 = 65536;               // 64KB dynamic LDS for glogits256

    size_t off = 0;
    auto alloc = [&](size_t bytes) { size_t o = off; off += (bytes + 255) & ~(size_t)255; return o; };

    size_t o_meanC = alloc((size_t)B * C * 4);
    size_t o_rstdC = alloc((size_t)B * C * 4);
    size_t o_meanS = alloc((size_t)B * C * 4);
    size_t o_rstdS = alloc((size_t)B * C * 4);
    size_t o_cwT = alloc(W2 * 2);
    size_t o_swT = alloc(W2 * 2);
    size_t o_iwT = alloc(W2 * 2);
    size_t o_ow  = alloc(W2 * 2);
    size_t o_G   = alloc(W2 * 2);
    size_t o_W   = alloc(W2 * 2);
    size_t o_v   = alloc((size_t)C * 4);
    size_t o_wu  = alloc((size_t)C * 4);
    size_t o_u   = alloc((size_t)B * N * 4);
    size_t o_cnT = alloc(B * NC * 2);
    size_t o_snT = alloc(B * NC * 2);
    size_t o_sRT = alloc(B * NC * 2);
    size_t o_sgT = alloc(B * NC * 2);
    size_t o_sW  = alloc(B * NC * 2);
    size_t o_P   = alloc(2 * NN * 2);        // PAIR logits/P f16 (67MB)
    size_t o_pt  = alloc(8 * NC * 2);        // pair split-K4 partials f16

    if (ws_size < off) {
        (void)hipMemsetAsync(d_out, 0, (size_t)out_size * 4, stream);
        return;
    }

    float* meanC = (float*)(ws + o_meanC);
    float* rstdC = (float*)(ws + o_rstdC);
    float* meanS = (float*)(ws + o_meanS);
    float* rstdS = (float*)(ws + o_rstdS);
    u16* cwT = (u16*)(ws + o_cwT);
    u16* swT = (u16*)(ws + o_swT);
    u16* iwT = (u16*)(ws + o_iwT);
    u16* ow  = (u16*)(ws + o_ow);
    u16* Gf  = (u16*)(ws + o_G);
    u16* Wf  = (u16*)(ws + o_W);
    float* vb = (float*)(ws + o_v);
    float* wu = (float*)(ws + o_wu);
    float* ub = (float*)(ws + o_u);
    u16* cnT = (u16*)(ws + o_cnT);
    u16* snT = (u16*)(ws + o_snT);
    u16* sRT = (u16*)(ws + o_sRT);
    u16* sgT = (u16*)(ws + o_sgT);
    u16* sW  = (u16*)(ws + o_sW);
    u16* Pb  = (u16*)(ws + o_P);
    u16* partH = (u16*)(ws + o_pt);

    // 1) instance-norm stats
    stats_kernel<<<dim3(B * C, 2), 256, 0, stream>>>(c, s, meanC, rstdC, meanS, rstdS);
    // 2) fused packs
    packall<<<dim3(N / 32, C / 32, 8), dim3(32, 8), 0, stream>>>(
        c, s, meanC, rstdC, meanS, rstdS, cnT, snT, sRT);
    // 3) fused weight preps
    prep_kernel<<<dim3(16, 16, 4), dim3(32, 8), 0, stream>>>(
        c_w, s_w, i_w, o_w, cwT, swT, iwT, ow);
    bias_prep<<<dim3(4), 256, 0, stream>>>(o_w, i_b, o_b, s_w, c_b, vb, wu);
    // G and W in one dispatch
    gemm_bt<EPI_PLAIN_F16><<<dim3(4, 2, 2), 512, 0, stream>>>(
        cwT, swT, 512, 512, nullptr, nullptr, 0, nullptr, Gf, 512, 1,
        (long)(3 * W2), 0, (long)W2, 0, (long)W2);
    // 4) sgT[m,a] = sum_l snT[m,l]*G[a,l]
    gemm_bt<EPI_PLAIN_F16><<<dim3(4, 16, B), 512, 0, stream>>>(
        snT, Gf, 512, 512, nullptr, nullptr, 0, nullptr, sgT, 512, 1,
        (long)NC, 0, 0, 0, (long)NC);
    // 5) sW[o,m] = sum_c W[o,c]*sRT[m,c]
    gemm_bt<EPI_PLAIN_F16><<<dim3(32, 2, B), 512, 0, stream>>>(
        Wf, sRT, 512, 512, nullptr, nullptr, 0, nullptr, sW, 4096, 1,
        0, 0, (long)NC, 0, (long)NC);
    // 6) u[b,m] = sum_l snT[b,m,l]*wu[l]
    rowdot_kernel<<<dim3(B * N / 4), 256, 0, stream>>>(snT, wu, ub);
    // 7) attention in batch PAIRS — 256^2 2-phase logits, R12 engine PV
    for (int pb0 = 0; pb0 < B; pb0 += 2) {
        // logits: L[z,n,m] = cn.sg + u[m]  (M=N=4096, K=512)
        glogits256<<<dim3(16, 16, 2), 512, SMEM256, stream>>>(
            cnT + (size_t)pb0 * NC, sgT + (size_t)pb0 * NC,
            ub + (size_t)pb0 * N, Pb,
            (long)NC, (long)NC, (long)N, (long)NN);
        // P = softmax_m(L) in place, 8192 rows
        softmax16<<<dim3(2 * N), 256, 0, stream>>>(Pb);
        // out_pre[o,n] = sum_m sW[o,m]*P[n,m]; split-K4, pair in one dispatch
        gemm_bt<EPI_PLAIN_F16><<<dim3(32, 2, 8), 512, 0, stream>>>(
            sW + (size_t)pb0 * NC, Pb, 1024, 4096, nullptr, nullptr, 0,
            nullptr, partH, 4096, 4,
            (long)NC, 1024L, (long)NN, 1024L, (long)NC);
        // out = sum partials + x + v
        reduce4resid<<<dim3((int)(NC / 2048), 2), 256, 0, stream>>>(
            partH, x + (size_t)pb0 * NC, vb, out + (size_t)pb0 * NC);
    }
}